// Round 1
// baseline (996.586 us; speedup 1.0000x reference)
//
#include <hip/hip_runtime.h>

typedef float f32x4 __attribute__((ext_vector_type(4)));
typedef short bfrag __attribute__((ext_vector_type(8)));
typedef unsigned short u16;

__device__ __forceinline__ u16 f2bf(float f) {
  union { float f; unsigned u; } x; x.f = f;
  unsigned r = x.u + 0x7fffu + ((x.u >> 16) & 1u);
  return (u16)(r >> 16);
}

__device__ __forceinline__ void g2l16(const void* g, void* l) {
  void* gnc = const_cast<void*>(g);
  __builtin_amdgcn_global_load_lds((__attribute__((address_space(1))) void*)gnc,
                                   (__attribute__((address_space(3))) void*)l, 16, 0, 0);
}

__device__ __forceinline__ f32x4 mfma16(bfrag a, bfrag b, f32x4 c) {
  asm volatile("v_mfma_f32_16x16x32_bf16 %0, %1, %2, %0" : "+v"(c) : "v"(a), "v"(b));
  return c;
}

__device__ __forceinline__ float wred_sum(float s) {
  #pragma unroll
  for (int o = 32; o; o >>= 1) s += __shfl_xor(s, o);
  return s;
}

// ---------------- f32 -> bf16 convert ----------------
__global__ __launch_bounds__(256) void cvt_k(const float* __restrict__ s,
                                             u16* __restrict__ d, int n) {
  int i = (blockIdx.x * 256 + threadIdx.x) * 4;
  float4 f = *(const float4*)(s + i);
  ushort4 o;
  o.x = f2bf(f.x); o.y = f2bf(f.y); o.z = f2bf(f.z); o.w = f2bf(f.w);
  *(ushort4*)(d + i) = o;
}

// ---------------- uncertainty gate -> log(g+1e-9) ----------------
__device__ __forceinline__ float softplus_s(float x) {
  return fmaxf(x, 0.f) + log1pf(expf(-fabsf(x)));
}

__global__ __launch_bounds__(256) void gate_k(const float* __restrict__ h,
                                              const float* __restrict__ w4,
                                              const float* __restrict__ b4,
                                              float* __restrict__ logg) {
  const int lane = threadIdx.x & 63, wv = threadIdx.x >> 6;
  const size_t tok = (size_t)blockIdx.x * 4 + wv;
  const float* x = h + tok * 512;
  float s0 = 0.f, s1 = 0.f, s2 = 0.f, s3 = 0.f;
  #pragma unroll
  for (int i = 0; i < 8; ++i) {
    int c = (i << 6) + lane;
    float xv = x[c];
    s0 += xv * w4[c];
    s1 += xv * w4[512 + c];
    s2 += xv * w4[1024 + c];
    s3 += xv * w4[1536 + c];
  }
  s0 = wred_sum(s0); s1 = wred_sum(s1); s2 = wred_sum(s2); s3 = wred_sum(s3);
  if (lane == 0) {
    float mu = s0 + b4[0];
    float va = softplus_s(s1 + b4[1]) + 1e-6f;
    float al = softplus_s(s2 + b4[2]) + 1.f + 1e-6f;
    float be = softplus_s(s3 + b4[3]) + 1e-6f;
    float se2 = be / (va * (al - 1.f));
    float g = (1.f / (1.f + expf(-mu))) * expf(-se2);
    g = fminf(fmaxf(g, 1e-3f), 1.f);
    logg[tok] = logf(g + 1e-9f);
  }
}

// ---------------- residual + LayerNorm ----------------
template <bool WB>
__global__ __launch_bounds__(256) void ln_k(const float* __restrict__ res,
                                            const float* __restrict__ y,
                                            const float* __restrict__ sc,
                                            const float* __restrict__ bi,
                                            float* __restrict__ out,
                                            u16* __restrict__ out16) {
  const int lane = threadIdx.x & 63, w = threadIdx.x >> 6;
  const size_t row = (size_t)blockIdx.x * 4 + w;
  const float* xr = res + row * 512;
  const float* yr = y + row * 512;
  float v[8];
  float s = 0.f;
  #pragma unroll
  for (int i = 0; i < 8; ++i) {
    int c = (i << 6) + lane;
    v[i] = xr[c] + yr[c];
    s += v[i];
  }
  s = wred_sum(s);
  float m = s * (1.f / 512.f);
  float s2 = 0.f;
  #pragma unroll
  for (int i = 0; i < 8; ++i) { float d = v[i] - m; s2 += d * d; }
  s2 = wred_sum(s2);
  float inv = rsqrtf(s2 * (1.f / 512.f) + 1e-5f);
  #pragma unroll
  for (int i = 0; i < 8; ++i) {
    int c = (i << 6) + lane;
    float o2 = (v[i] - m) * inv * sc[c] + bi[c];
    out[row * 512 + c] = o2;
    if constexpr (WB) out16[row * 512 + c] = f2bf(o2);
  }
}

// ---------------- row softmax with gate bias + mask -> bf16 P ----------------
__global__ __launch_bounds__(256) void softmax_k(const float* __restrict__ S,
                                                 u16* __restrict__ P,
                                                 const float* __restrict__ logg,
                                                 const int* __restrict__ mask,
                                                 int Lk, int Lq, int H, int zbase,
                                                 float scale) {
  const int tid = threadIdx.x;
  const int row = blockIdx.x;
  const int lz = row / Lq;
  const int gz = zbase + lz;
  const int b = gz / H;
  const float* s = S + (size_t)row * Lk;
  const float* lg = logg + (size_t)b * Lk;
  const int* mk = mask + (size_t)b * Lk;
  const int ne = Lk >> 8;  // 1 or 4
  float v[4];
  float mx = -3.0e38f;
  for (int i = 0; i < ne; ++i) {
    int j = tid + (i << 8);
    float t = mk[j] ? fmaf(s[j], scale, lg[j]) : -1e9f;
    v[i] = t;
    mx = fmaxf(mx, t);
  }
  __shared__ float red[4];
  #pragma unroll
  for (int o = 32; o; o >>= 1) mx = fmaxf(mx, __shfl_xor(mx, o));
  if ((tid & 63) == 0) red[tid >> 6] = mx;
  __syncthreads();
  mx = fmaxf(fmaxf(red[0], red[1]), fmaxf(red[2], red[3]));
  __syncthreads();
  float sum = 0.f;
  for (int i = 0; i < ne; ++i) { v[i] = expf(v[i] - mx); sum += v[i]; }
  sum = wred_sum(sum);
  if ((tid & 63) == 0) red[tid >> 6] = sum;
  __syncthreads();
  sum = red[0] + red[1] + red[2] + red[3];
  float inv = 1.f / sum;
  for (int i = 0; i < ne; ++i) {
    int j = tid + (i << 8);
    P[(size_t)row * Lk + j] = f2bf(v[i] * inv);
  }
}

// ---------------- MFMA GEMM: C[m,n] = sum_k A[m,k]*W[n,k] (+bias) ----------------
// EPI: 0 = f32 store, 1 = bf16 store, 2 = gelu->bf16, 3 = per-head transpose ->bf16
template <int WM, int WN, int FM, int FN, int EPI>
__global__ __launch_bounds__(256) void gemm_k(
    const u16* __restrict__ A, const u16* __restrict__ W,
    const float* __restrict__ bias, void* __restrict__ C,
    int K, int lda, int ldw, int ldc,
    long long sAb, long long sAh, long long sAl,
    long long sWb, long long sWh, long long sWl,
    long long sCb, long long sCh, long long sCl,
    int H, int zbase, int TR) {
  constexpr int BM = WM * FM * 16;
  constexpr int BN = WN * FN * 16;
  __shared__ __align__(16) u16 Al[BM * 32];
  __shared__ __align__(16) u16 Wl[BN * 32];
  const int tid = threadIdx.x;
  const int lz = blockIdx.z;
  const int gz = zbase + lz;
  const int zb = gz / H, zh = gz - zb * H;
  const u16* Ab = A + (size_t)zb * sAb + (size_t)zh * sAh + (size_t)lz * sAl;
  const u16* Wb = W + (size_t)zb * sWb + (size_t)zh * sWh + (size_t)lz * sWl;
  const long long coff = (long long)zb * sCb + (long long)zh * sCh + (long long)lz * sCl;
  const int row0 = blockIdx.y * BM;
  const int col0 = blockIdx.x * BN;
  const int lane = tid & 63;
  const int wv = tid >> 6;
  const int wr = wv / WN, wc = wv % WN;
  const int rowW = wr * FM * 16, colW = wc * FN * 16;
  const int lr = lane & 15, lk = (lane >> 4) * 8;

  f32x4 acc[FM][FN] = {};

  for (int k0 = 0; k0 < K; k0 += 32) {
    #pragma unroll
    for (int r = 0; r < BM / 64; ++r) {
      int o = r * 4096 + tid * 16;
      int arow = o >> 6, ab = o & 63;
      const char* src = (const char*)(Ab + (size_t)(row0 + arow) * lda + k0) + ab;
      g2l16(src, (char*)Al + o);
    }
    #pragma unroll
    for (int r = 0; r < BN / 64; ++r) {
      int o = r * 4096 + tid * 16;
      int wrow = o >> 6, wb2 = o & 63;
      const char* src = (const char*)(Wb + (size_t)(col0 + wrow) * ldw + k0) + wb2;
      g2l16(src, (char*)Wl + o);
    }
    __syncthreads();
    bfrag af[FM], wf[FN];
    #pragma unroll
    for (int m = 0; m < FM; ++m)
      af[m] = *(const bfrag*)(Al + (rowW + m * 16 + lr) * 32 + lk);
    #pragma unroll
    for (int n = 0; n < FN; ++n)
      wf[n] = *(const bfrag*)(Wl + (colW + n * 16 + lr) * 32 + lk);
    #pragma unroll
    for (int m = 0; m < FM; ++m)
      #pragma unroll
      for (int n = 0; n < FN; ++n)
        acc[m][n] = mfma16(af[m], wf[n], acc[m][n]);
    __syncthreads();
  }
  asm volatile("s_nop 7\n\ts_nop 7\n\ts_nop 7");

  #pragma unroll
  for (int m = 0; m < FM; ++m) {
    #pragma unroll
    for (int n = 0; n < FN; ++n) {
      int rb = row0 + rowW + m * 16 + (lane >> 4) * 4;
      int c = col0 + colW + n * 16 + lr;
      float bv = bias ? bias[c] : 0.f;
      if constexpr (EPI == 0) {
        float* Cf = (float*)C;
        #pragma unroll
        for (int e = 0; e < 4; ++e)
          Cf[coff + (long long)(rb + e) * ldc + c] = acc[m][n][e] + bv;
      } else if constexpr (EPI == 1) {
        u16* Cu = (u16*)C;
        #pragma unroll
        for (int e = 0; e < 4; ++e)
          Cu[coff + (long long)(rb + e) * ldc + c] = f2bf(acc[m][n][e] + bv);
      } else if constexpr (EPI == 2) {
        u16* Cu = (u16*)C;
        #pragma unroll
        for (int e = 0; e < 4; ++e) {
          float vv = acc[m][n][e] + bv;
          float gl = 0.5f * vv * (1.f + erff(vv * 0.70710678118f));
          Cu[coff + (long long)(rb + e) * ldc + c] = f2bf(gl);
        }
      } else {  // EPI == 3 : store V^T per head: vt[((b*8+h)*64+d)*TR + j]
        u16* Cu = (u16*)C;
        int b2 = rb / TR, j0 = rb - b2 * TR;
        int h2 = c >> 6, dd = c & 63;
        ushort4 pk;
        pk.x = f2bf(acc[m][n][0] + bv);
        pk.y = f2bf(acc[m][n][1] + bv);
        pk.z = f2bf(acc[m][n][2] + bv);
        pk.w = f2bf(acc[m][n][3] + bv);
        *(ushort4*)&Cu[(((size_t)b2 * 8 + h2) * 64 + dd) * TR + j0] = pk;
      }
    }
  }
}

// =============================== host ===============================
extern "C" void kernel_launch(void* const* d_in, const int* in_sizes, int n_in,
                              void* d_out, int out_size, void* d_ws, size_t ws_size,
                              hipStream_t stream) {
  const float* h_d = (const float*)d_in[0];
  const float* h_p = (const float*)d_in[1];
  const float* gd_w = (const float*)d_in[2];
  const float* gd_b = (const float*)d_in[3];
  const float* gp_w = (const float*)d_in[4];
  const float* gp_b = (const float*)d_in[5];
  const float* wqd_w = (const float*)d_in[6];  const float* wqd_b = (const float*)d_in[7];
  const float* wkp_w = (const float*)d_in[8];  const float* wkp_b = (const float*)d_in[9];
  const float* wvp_w = (const float*)d_in[10]; const float* wvp_b = (const float*)d_in[11];
  const float* wqp_w = (const float*)d_in[12]; const float* wqp_b = (const float*)d_in[13];
  const float* wkd_w = (const float*)d_in[14]; const float* wkd_b = (const float*)d_in[15];
  const float* wvd_w = (const float*)d_in[16]; const float* wvd_b = (const float*)d_in[17];
  const float* od_w = (const float*)d_in[18];  const float* od_b = (const float*)d_in[19];
  const float* op_w = (const float*)d_in[20];  const float* op_b = (const float*)d_in[21];
  const float* fd1_w = (const float*)d_in[22]; const float* fd1_b = (const float*)d_in[23];
  const float* fd2_w = (const float*)d_in[24]; const float* fd2_b = (const float*)d_in[25];
  const float* fp1_w = (const float*)d_in[26]; const float* fp1_b = (const float*)d_in[27];
  const float* fp2_w = (const float*)d_in[28]; const float* fp2_b = (const float*)d_in[29];
  const float* nd1_s = (const float*)d_in[30]; const float* nd1_b = (const float*)d_in[31];
  const float* nd2_s = (const float*)d_in[32]; const float* nd2_b = (const float*)d_in[33];
  const float* np1_s = (const float*)d_in[34]; const float* np1_b = (const float*)d_in[35];
  const float* np2_s = (const float*)d_in[36]; const float* np2_b = (const float*)d_in[37];
  const int* mask_d = (const int*)d_in[38];
  const int* mask_p = (const int*)d_in[39];

  constexpr int B = 16, Ld = 256, Lp = 1024, D = 512, H = 8, F = 2048;
  constexpr int Md = B * Ld;   // 4096
  constexpr int Mp = B * Lp;   // 16384
  constexpr int BH = B * H;    // 128

  char* ws = (char*)d_ws;
  size_t off = 0;
  auto alloc = [&](size_t bytes) {
    size_t o = off;
    off += (bytes + 255) & ~(size_t)255;
    return o;
  };
  auto a16 = [&](size_t els) { return (u16*)(ws + alloc(els * 2)); };
  auto a32 = [&](size_t els) { return (float*)(ws + alloc(els * 4)); };

  u16* w_qd = a16((size_t)D * D);
  u16* w_kp = a16((size_t)D * D);
  u16* w_vp = a16((size_t)D * D);
  u16* w_qp = a16((size_t)D * D);
  u16* w_kd = a16((size_t)D * D);
  u16* w_vd = a16((size_t)D * D);
  u16* w_od = a16((size_t)D * D);
  u16* w_op = a16((size_t)D * D);
  u16* w_fd1 = a16((size_t)F * D);
  u16* w_fd2 = a16((size_t)F * D);
  u16* w_fp1 = a16((size_t)F * D);
  u16* w_fp2 = a16((size_t)F * D);

  u16* hd16 = a16((size_t)Md * D);    // later: attn1 out (bf16)
  u16* hd2_16 = a16((size_t)Md * D);
  u16* hp16 = a16((size_t)Mp * D);    // later: attn2 out, then hp2 bf16
  u16* qd16 = a16((size_t)Md * D);    // later: kd16
  u16* kp16 = a16((size_t)Mp * D);    // later: qp16
  u16* vt16 = a16((size_t)Mp * D);    // vt1 [B,H,64,Lp]; later vt2 [B,H,64,Ld]
  float* obuf = a32((size_t)Mp * D);  // od, op, d2, p2 (sequential lifetimes)
  float* hd2 = a32((size_t)Md * D);
  float* hp2 = a32((size_t)Mp * D);
  u16* t16 = a16((size_t)Mp * F);     // ffn hidden (bf16, post-gelu)
  float* logg_d = a32(Md);
  float* logg_p = a32(Mp);

  // pick attention chunking to fit workspace (S fp32 + P bf16)
  int NC = 8;
  const int cand[4] = {1, 2, 4, 8};
  for (int i = 0; i < 4; ++i) {
    size_t se = (size_t)(BH / cand[i]) * 262144ULL;
    size_t need = off + ((se * 4 + 255) & ~(size_t)255) + ((se * 2 + 255) & ~(size_t)255);
    if (need <= ws_size) { NC = cand[i]; break; }
  }
  const int Z = BH / NC;
  float* Sb = a32((size_t)Z * 262144ULL);
  u16* Pb = a16((size_t)Z * 262144ULL);

  // --- conversions (inputs + all weights) ---
  {
    const float* src[14] = {h_d, h_p, wqd_w, wkp_w, wvp_w, wqp_w, wkd_w,
                            wvd_w, od_w, op_w, fd1_w, fd2_w, fp1_w, fp2_w};
    u16* dst[14] = {hd16, hp16, w_qd, w_kp, w_vp, w_qp, w_kd,
                    w_vd, w_od, w_op, w_fd1, w_fd2, w_fp1, w_fp2};
    const int nn[14] = {Md * D, Mp * D, D * D, D * D, D * D, D * D, D * D,
                        D * D, D * D, D * D, F * D, F * D, F * D, F * D};
    for (int i = 0; i < 14; ++i)
      cvt_k<<<nn[i] / 1024, 256, 0, stream>>>(src[i], dst[i], nn[i]);
  }

  // --- gates (from ORIGINAL inputs) ---
  gate_k<<<Md / 4, 256, 0, stream>>>(h_d, gd_w, gd_b, logg_d);
  gate_k<<<Mp / 4, 256, 0, stream>>>(h_p, gp_w, gp_b, logg_p);

  // --- projections for attn1 ---
  gemm_k<2, 2, 2, 2, 1><<<dim3(D / 64, Md / 64, 1), 256, 0, stream>>>(
      hd16, w_qd, wqd_b, qd16, D, D, D, D, 0, 0, 0, 0, 0, 0, 0, 0, 0, 1, 0, 0);
  gemm_k<2, 2, 4, 4, 1><<<dim3(D / 128, Mp / 128, 1), 256, 0, stream>>>(
      hp16, w_kp, wkp_b, kp16, D, D, D, D, 0, 0, 0, 0, 0, 0, 0, 0, 0, 1, 0, 0);
  gemm_k<2, 2, 4, 4, 3><<<dim3(D / 128, Mp / 128, 1), 256, 0, stream>>>(
      hp16, w_vp, wvp_b, vt16, D, D, D, 0, 0, 0, 0, 0, 0, 0, 0, 0, 0, 1, 0, Lp);

  // --- attn1: drug attends protein (Lq=256, Lk=1024) ---
  for (int c2 = 0; c2 < NC; ++c2) {
    int zb2 = c2 * Z;
    gemm_k<2, 2, 4, 4, 0><<<dim3(Lp / 128, Ld / 128, Z), 256, 0, stream>>>(
        qd16, kp16, nullptr, Sb, 64, D, D, Lp,
        (long long)Ld * D, 64, 0,
        (long long)Lp * D, 64, 0,
        0, 0, (long long)Ld * Lp, H, zb2, 0);
    softmax_k<<<Z * Ld, 256, 0, stream>>>(Sb, Pb, logg_p, mask_p, Lp, Ld, H, zb2, 0.125f);
    gemm_k<2, 2, 2, 2, 1><<<dim3(1, Ld / 64, Z), 256, 0, stream>>>(
        Pb, vt16, nullptr, hd16, Lp, Lp, Lp, D,
        0, 0, (long long)Ld * Lp,
        (long long)H * 64 * Lp, (long long)64 * Lp, 0,
        (long long)Ld * D, 64, 0, H, zb2, 0);
  }

  // --- o-proj + LN1 -> h_d' ---
  gemm_k<2, 2, 2, 2, 0><<<dim3(D / 64, Md / 64, 1), 256, 0, stream>>>(
      hd16, w_od, od_b, obuf, D, D, D, D, 0, 0, 0, 0, 0, 0, 0, 0, 0, 1, 0, 0);
  ln_k<true><<<Md / 4, 256, 0, stream>>>(h_d, obuf, nd1_s, nd1_b, hd2, hd2_16);

  // --- projections for attn2 (K/V from UPDATED drug) ---
  gemm_k<2, 2, 4, 4, 1><<<dim3(D / 128, Mp / 128, 1), 256, 0, stream>>>(
      hp16, w_qp, wqp_b, kp16, D, D, D, D, 0, 0, 0, 0, 0, 0, 0, 0, 0, 1, 0, 0);
  gemm_k<2, 2, 2, 2, 1><<<dim3(D / 64, Md / 64, 1), 256, 0, stream>>>(
      hd2_16, w_kd, wkd_b, qd16, D, D, D, D, 0, 0, 0, 0, 0, 0, 0, 0, 0, 1, 0, 0);
  gemm_k<2, 2, 2, 2, 3><<<dim3(D / 64, Md / 64, 1), 256, 0, stream>>>(
      hd2_16, w_vd, wvd_b, vt16, D, D, D, 0, 0, 0, 0, 0, 0, 0, 0, 0, 0, 1, 0, Ld);

  // --- attn2: protein attends drug (Lq=1024, Lk=256) ---
  for (int c2 = 0; c2 < NC; ++c2) {
    int zb2 = c2 * Z;
    gemm_k<2, 2, 4, 4, 0><<<dim3(Ld / 128, Lp / 128, Z), 256, 0, stream>>>(
        kp16, qd16, nullptr, Sb, 64, D, D, Ld,
        (long long)Lp * D, 64, 0,
        (long long)Ld * D, 64, 0,
        0, 0, (long long)Lp * Ld, H, zb2, 0);
    softmax_k<<<Z * Lp, 256, 0, stream>>>(Sb, Pb, logg_d, mask_d, Ld, Lp, H, zb2, 0.125f);
    gemm_k<2, 2, 2, 2, 1><<<dim3(1, Lp / 64, Z), 256, 0, stream>>>(
        Pb, vt16, nullptr, hp16, Ld, Ld, Ld, D,
        0, 0, (long long)Lp * Ld,
        (long long)H * 64 * Ld, (long long)64 * Ld, 0,
        (long long)Lp * D, 64, 0, H, zb2, 0);
  }

  // --- o-proj + LN2 -> h_p' (bf16 into hp16 slot) ---
  gemm_k<2, 2, 4, 4, 0><<<dim3(D / 128, Mp / 128, 1), 256, 0, stream>>>(
      hp16, w_op, op_b, obuf, D, D, D, D, 0, 0, 0, 0, 0, 0, 0, 0, 0, 1, 0, 0);
  ln_k<true><<<Mp / 4, 256, 0, stream>>>(h_p, obuf, np1_s, np1_b, hp2, hp16);

  // --- FFN drug + final LN -> d_out[0 : Md*D] ---
  gemm_k<2, 2, 4, 4, 2><<<dim3(F / 128, Md / 128, 1), 256, 0, stream>>>(
      hd2_16, w_fd1, fd1_b, t16, D, D, D, F, 0, 0, 0, 0, 0, 0, 0, 0, 0, 1, 0, 0);
  gemm_k<2, 2, 2, 2, 0><<<dim3(D / 64, Md / 64, 1), 256, 0, stream>>>(
      t16, w_fd2, fd2_b, obuf, F, F, F, D, 0, 0, 0, 0, 0, 0, 0, 0, 0, 1, 0, 0);
  ln_k<false><<<Md / 4, 256, 0, stream>>>(hd2, obuf, nd2_s, nd2_b, (float*)d_out, nullptr);

  // --- FFN protein + final LN -> d_out[Md*D : ] ---
  gemm_k<2, 2, 4, 4, 2><<<dim3(F / 128, Mp / 128, 1), 256, 0, stream>>>(
      hp16, w_fp1, fp1_b, t16, D, D, D, F, 0, 0, 0, 0, 0, 0, 0, 0, 0, 1, 0, 0);
  gemm_k<2, 2, 4, 4, 0><<<dim3(D / 128, Mp / 128, 1), 256, 0, stream>>>(
      t16, w_fp2, fp2_b, obuf, F, F, F, D, 0, 0, 0, 0, 0, 0, 0, 0, 0, 1, 0, 0);
  ln_k<false><<<Mp / 4, 256, 0, stream>>>(hp2, obuf, np2_s, np2_b,
                                          (float*)d_out + (size_t)Md * D, nullptr);
}

// Round 2
// 449.640 us; speedup vs baseline: 2.2164x; 2.2164x over previous
//
#include <hip/hip_runtime.h>

typedef float f32x4 __attribute__((ext_vector_type(4)));
typedef short bfrag __attribute__((ext_vector_type(8)));
typedef unsigned short u16;

__device__ __forceinline__ u16 f2bf(float f) {
  union { float f; unsigned u; } x; x.f = f;
  unsigned r = x.u + 0x7fffu + ((x.u >> 16) & 1u);
  return (u16)(r >> 16);
}

__device__ __forceinline__ void g2l16(const void* g, void* l) {
  void* gnc = const_cast<void*>(g);
  __builtin_amdgcn_global_load_lds((__attribute__((address_space(1))) void*)gnc,
                                   (__attribute__((address_space(3))) void*)l, 16, 0, 0);
}

__device__ __forceinline__ f32x4 mfma16(bfrag a, bfrag b, f32x4 c) {
  asm volatile("v_mfma_f32_16x16x32_bf16 %0, %1, %2, %0" : "+v"(c) : "v"(a), "v"(b));
  return c;
}

__device__ __forceinline__ float wred_sum(float s) {
  #pragma unroll
  for (int o = 32; o; o >>= 1) s += __shfl_xor(s, o);
  return s;
}

// ---------------- f32 -> bf16 convert ----------------
__global__ __launch_bounds__(256) void cvt_k(const float* __restrict__ s,
                                             u16* __restrict__ d, int n) {
  int i = (blockIdx.x * 256 + threadIdx.x) * 4;
  float4 f = *(const float4*)(s + i);
  ushort4 o;
  o.x = f2bf(f.x); o.y = f2bf(f.y); o.z = f2bf(f.z); o.w = f2bf(f.w);
  *(ushort4*)(d + i) = o;
}

// ---------------- uncertainty gate -> log(g+1e-9) ----------------
__device__ __forceinline__ float softplus_s(float x) {
  return fmaxf(x, 0.f) + log1pf(expf(-fabsf(x)));
}

__global__ __launch_bounds__(256) void gate_k(const float* __restrict__ h,
                                              const float* __restrict__ w4,
                                              const float* __restrict__ b4,
                                              float* __restrict__ logg) {
  const int lane = threadIdx.x & 63, wv = threadIdx.x >> 6;
  const size_t tok = (size_t)blockIdx.x * 4 + wv;
  const float* x = h + tok * 512;
  float s0 = 0.f, s1 = 0.f, s2 = 0.f, s3 = 0.f;
  #pragma unroll
  for (int i = 0; i < 8; ++i) {
    int c = (i << 6) + lane;
    float xv = x[c];
    s0 += xv * w4[c];
    s1 += xv * w4[512 + c];
    s2 += xv * w4[1024 + c];
    s3 += xv * w4[1536 + c];
  }
  s0 = wred_sum(s0); s1 = wred_sum(s1); s2 = wred_sum(s2); s3 = wred_sum(s3);
  if (lane == 0) {
    float mu = s0 + b4[0];
    float va = softplus_s(s1 + b4[1]) + 1e-6f;
    float al = softplus_s(s2 + b4[2]) + 1.f + 1e-6f;
    float be = softplus_s(s3 + b4[3]) + 1e-6f;
    float se2 = be / (va * (al - 1.f));
    float g = (1.f / (1.f + expf(-mu))) * expf(-se2);
    g = fminf(fmaxf(g, 1e-3f), 1.f);
    logg[tok] = logf(g + 1e-9f);
  }
}

// ---------------- residual + LayerNorm ----------------
template <bool WB>
__global__ __launch_bounds__(256) void ln_k(const float* __restrict__ res,
                                            const float* __restrict__ y,
                                            const float* __restrict__ sc,
                                            const float* __restrict__ bi,
                                            float* __restrict__ out,
                                            u16* __restrict__ out16) {
  const int lane = threadIdx.x & 63, w = threadIdx.x >> 6;
  const size_t row = (size_t)blockIdx.x * 4 + w;
  const float* xr = res + row * 512;
  const float* yr = y + row * 512;
  float v[8];
  float s = 0.f;
  #pragma unroll
  for (int i = 0; i < 8; ++i) {
    int c = (i << 6) + lane;
    v[i] = xr[c] + yr[c];
    s += v[i];
  }
  s = wred_sum(s);
  float m = s * (1.f / 512.f);
  float s2 = 0.f;
  #pragma unroll
  for (int i = 0; i < 8; ++i) { float d = v[i] - m; s2 += d * d; }
  s2 = wred_sum(s2);
  float inv = rsqrtf(s2 * (1.f / 512.f) + 1e-5f);
  #pragma unroll
  for (int i = 0; i < 8; ++i) {
    int c = (i << 6) + lane;
    float o2 = (v[i] - m) * inv * sc[c] + bi[c];
    out[row * 512 + c] = o2;
    if constexpr (WB) out16[row * 512 + c] = f2bf(o2);
  }
}

// ---------------- fused flash cross-attention ----------------
// Q:[B*Lq][512] (head h at col h*64), K:[B*Lk][512], Vt:[(b*8+h)*64+dd][Lk]
// Out[b*Lq+q][h*64+dd] = softmax(QK^T/8 + log g[k] ; mask) @ V
template <int KT>
__global__ __launch_bounds__(256) void flash_k(
    const u16* __restrict__ Q, const u16* __restrict__ Kv,
    const u16* __restrict__ Vt, const float* __restrict__ logg,
    const int* __restrict__ mask, u16* __restrict__ Out,
    int Lq, int Lk, float scale) {
  __shared__ __align__(16) u16 Kl[KT * 64];        // [KT][64] chunks xor-swizzled
  __shared__ __align__(16) u16 Vl[64 * KT];        // [64][KT] chunks xor-swizzled
  __shared__ __align__(16) u16 Pl[64 * (KT + 8)];  // padded pitch
  const int tid = threadIdx.x;
  const int lane = tid & 63, wv = tid >> 6;
  const int lr = lane & 15, lg4 = lane >> 4;
  const int bh = blockIdx.z;
  const int b = bh >> 3, h = bh & 7;
  const int q0 = blockIdx.x * 64;

  // Q fragments (A-operand), held across the k-loop
  bfrag af[2];
  {
    const u16* qrow = Q + (size_t)(b * Lq + q0 + wv * 16 + lr) * 512 + h * 64;
    af[0] = *(const bfrag*)(qrow + lg4 * 8);
    af[1] = *(const bfrag*)(qrow + 32 + lg4 * 8);
  }
  float mreg[4] = {-3e38f, -3e38f, -3e38f, -3e38f};
  float lreg[4] = {0.f, 0.f, 0.f, 0.f};
  f32x4 Oa[4] = {};
  const float* lgb = logg + (size_t)b * Lk;
  const int* mkb = mask + (size_t)b * Lk;

  const int NKT = Lk / KT;
  for (int t = 0; t < NKT; ++t) {
    const int k0 = t * KT;
    __syncthreads();  // all waves done reading Kl/Vl from previous tile
    // --- stage K tile [KT][64] ---
    {
      const char* kb = (const char*)(Kv + (size_t)(b * Lk + k0) * 512 + h * 64);
      #pragma unroll
      for (int r = 0; r < KT / 32; ++r) {
        int o = r * 4096 + tid * 16;
        int rr = o >> 7, cd = (o >> 4) & 7;
        int cs = cd ^ (rr & 7);
        g2l16(kb + (size_t)rr * 1024 + cs * 16, (char*)Kl + o);
      }
      const char* vb = (const char*)(Vt + (size_t)bh * 64 * Lk + k0);
      #pragma unroll
      for (int r = 0; r < KT / 32; ++r) {
        int o = r * 4096 + tid * 16;
        int rr = o >> 8, cd = (o >> 4) & 15;
        int cs = (cd & 8) | ((cd & 7) ^ (rr & 7));
        g2l16(vb + (size_t)rr * (Lk * 2) + cs * 16, (char*)Vl + o);
      }
    }
    __syncthreads();  // drains vmcnt before barrier (compiler-inserted)

    // --- S = Q K^T (rows q, cols kk) ---
    f32x4 sa[KT / 16];
    #pragma unroll
    for (int n = 0; n < KT / 16; ++n) {
      sa[n] = f32x4{0.f, 0.f, 0.f, 0.f};
      int row = n * 16 + lr;
      #pragma unroll
      for (int ks = 0; ks < 2; ++ks) {
        bfrag kf = *(const bfrag*)(Kl + row * 64 + (((ks * 4 + lg4) ^ (row & 7)) * 8));
        sa[n] = mfma16(af[ks], kf, sa[n]);
      }
    }
    asm volatile("s_nop 7\n\ts_nop 7");

    // --- online softmax (per lane: 4 q-rows e, cols n*16+lr) ---
    float pv[KT / 16][4];
    float nm[4] = {-3e38f, -3e38f, -3e38f, -3e38f};
    #pragma unroll
    for (int n = 0; n < KT / 16; ++n) {
      int kk = k0 + n * 16 + lr;
      float lgv = lgb[kk];
      int mkv = mkb[kk];
      #pragma unroll
      for (int e = 0; e < 4; ++e) {
        float tv = mkv ? fmaf(sa[n][e], scale, lgv) : -1e9f;
        pv[n][e] = tv;
        nm[e] = fmaxf(nm[e], tv);
      }
    }
    float fac[4], rs[4];
    #pragma unroll
    for (int e = 0; e < 4; ++e) {
      nm[e] = fmaxf(nm[e], __shfl_xor(nm[e], 1));
      nm[e] = fmaxf(nm[e], __shfl_xor(nm[e], 2));
      nm[e] = fmaxf(nm[e], __shfl_xor(nm[e], 4));
      nm[e] = fmaxf(nm[e], __shfl_xor(nm[e], 8));
      nm[e] = fmaxf(nm[e], mreg[e]);
      fac[e] = __expf(mreg[e] - nm[e]);
      mreg[e] = nm[e];
      rs[e] = 0.f;
    }
    #pragma unroll
    for (int n = 0; n < KT / 16; ++n)
      #pragma unroll
      for (int e = 0; e < 4; ++e) {
        float p = __expf(pv[n][e] - nm[e]);
        pv[n][e] = p;
        rs[e] += p;
      }
    #pragma unroll
    for (int e = 0; e < 4; ++e) {
      rs[e] += __shfl_xor(rs[e], 1);
      rs[e] += __shfl_xor(rs[e], 2);
      rs[e] += __shfl_xor(rs[e], 4);
      rs[e] += __shfl_xor(rs[e], 8);
      lreg[e] = lreg[e] * fac[e] + rs[e];
    }
    #pragma unroll
    for (int n2 = 0; n2 < 4; ++n2)
      #pragma unroll
      for (int e = 0; e < 4; ++e) Oa[n2][e] *= fac[e];

    // --- write P (bf16) to own-wave LDS rows, then PV ---
    {
      int prow = wv * 16 + lg4 * 4;
      #pragma unroll
      for (int n = 0; n < KT / 16; ++n)
        #pragma unroll
        for (int e = 0; e < 4; ++e)
          Pl[(prow + e) * (KT + 8) + n * 16 + lr] = f2bf(pv[n][e]);
    }
    #pragma unroll
    for (int ks = 0; ks < KT / 32; ++ks) {
      bfrag pf = *(const bfrag*)(Pl + (wv * 16 + lr) * (KT + 8) + (ks * 4 + lg4) * 8);
      #pragma unroll
      for (int n2 = 0; n2 < 4; ++n2) {
        int vrow = n2 * 16 + lr;
        int ch = ks * 4 + lg4;
        int chs = (ch & 8) | ((ch & 7) ^ (vrow & 7));
        bfrag vf = *(const bfrag*)(Vl + vrow * KT + chs * 8);
        Oa[n2] = mfma16(pf, vf, Oa[n2]);
      }
    }
  }
  asm volatile("s_nop 7\n\ts_nop 7");

  // --- epilogue: normalize and store ---
  float inv[4];
  #pragma unroll
  for (int e = 0; e < 4; ++e) inv[e] = 1.f / lreg[e];
  u16* ob = Out + (size_t)(b * Lq + q0 + wv * 16 + lg4 * 4) * 512 + h * 64;
  #pragma unroll
  for (int n2 = 0; n2 < 4; ++n2)
    #pragma unroll
    for (int e = 0; e < 4; ++e)
      ob[(size_t)e * 512 + n2 * 16 + lr] = f2bf(Oa[n2][e] * inv[e]);
}

// ---------------- MFMA GEMM: C[m,n] = sum_k A[m,k]*W[n,k] (+bias) ----------------
// BK=64, xor-swizzled LDS (2-way bank free). EPI: 0=f32, 1=bf16, 2=gelu->bf16,
// 3=per-head transposed V store ->bf16
template <int WM, int WN, int FM, int FN, int EPI>
__global__ __launch_bounds__(256) void gemm_k(
    const u16* __restrict__ A, const u16* __restrict__ W,
    const float* __restrict__ bias, void* __restrict__ C,
    int K, int lda, int ldw, int ldc,
    long long sAb, long long sAh, long long sAl,
    long long sWb, long long sWh, long long sWl,
    long long sCb, long long sCh, long long sCl,
    int H, int zbase, int TR) {
  constexpr int BM = WM * FM * 16;
  constexpr int BN = WN * FN * 16;
  __shared__ __align__(16) u16 Al[BM * 64];
  __shared__ __align__(16) u16 Wl[BN * 64];
  const int tid = threadIdx.x;
  const int lz = blockIdx.z;
  const int gz = zbase + lz;
  const int zb = gz / H, zh = gz - zb * H;
  const u16* Ab = A + (size_t)zb * sAb + (size_t)zh * sAh + (size_t)lz * sAl;
  const u16* Wb = W + (size_t)zb * sWb + (size_t)zh * sWh + (size_t)lz * sWl;
  const long long coff = (long long)zb * sCb + (long long)zh * sCh + (long long)lz * sCl;
  const int row0 = blockIdx.y * BM;
  const int col0 = blockIdx.x * BN;
  const int lane = tid & 63;
  const int wv = tid >> 6;
  const int wr = wv / WN, wc = wv % WN;
  const int rowW = wr * FM * 16, colW = wc * FN * 16;
  const int lr = lane & 15, lg4 = lane >> 4;

  f32x4 acc[FM][FN] = {};

  for (int k0 = 0; k0 < K; k0 += 64) {
    #pragma unroll
    for (int r = 0; r < BM / 32; ++r) {
      int o = r * 4096 + tid * 16;
      int arow = o >> 7, cd = (o >> 4) & 7;
      int cs = cd ^ (arow & 7);
      const char* src = (const char*)(Ab + (size_t)(row0 + arow) * lda + k0) + cs * 16;
      g2l16(src, (char*)Al + o);
    }
    #pragma unroll
    for (int r = 0; r < BN / 32; ++r) {
      int o = r * 4096 + tid * 16;
      int wrow = o >> 7, cd = (o >> 4) & 7;
      int cs = cd ^ (wrow & 7);
      const char* src = (const char*)(Wb + (size_t)(col0 + wrow) * ldw + k0) + cs * 16;
      g2l16(src, (char*)Wl + o);
    }
    __syncthreads();
    bfrag af[FM][2], wf[FN][2];
    #pragma unroll
    for (int m = 0; m < FM; ++m) {
      int row = rowW + m * 16 + lr;
      #pragma unroll
      for (int ks = 0; ks < 2; ++ks)
        af[m][ks] = *(const bfrag*)(Al + row * 64 + (((ks * 4 + lg4) ^ (row & 7)) * 8));
    }
    #pragma unroll
    for (int n = 0; n < FN; ++n) {
      int row = colW + n * 16 + lr;
      #pragma unroll
      for (int ks = 0; ks < 2; ++ks)
        wf[n][ks] = *(const bfrag*)(Wl + row * 64 + (((ks * 4 + lg4) ^ (row & 7)) * 8));
    }
    #pragma unroll
    for (int m = 0; m < FM; ++m)
      #pragma unroll
      for (int n = 0; n < FN; ++n) {
        acc[m][n] = mfma16(af[m][0], wf[n][0], acc[m][n]);
        acc[m][n] = mfma16(af[m][1], wf[n][1], acc[m][n]);
      }
    __syncthreads();
  }
  asm volatile("s_nop 7\n\ts_nop 7\n\ts_nop 7");

  #pragma unroll
  for (int m = 0; m < FM; ++m) {
    #pragma unroll
    for (int n = 0; n < FN; ++n) {
      int rb = row0 + rowW + m * 16 + (lane >> 4) * 4;
      int c = col0 + colW + n * 16 + lr;
      float bv = bias ? bias[c] : 0.f;
      if constexpr (EPI == 0) {
        float* Cf = (float*)C;
        #pragma unroll
        for (int e = 0; e < 4; ++e)
          Cf[coff + (long long)(rb + e) * ldc + c] = acc[m][n][e] + bv;
      } else if constexpr (EPI == 1) {
        u16* Cu = (u16*)C;
        #pragma unroll
        for (int e = 0; e < 4; ++e)
          Cu[coff + (long long)(rb + e) * ldc + c] = f2bf(acc[m][n][e] + bv);
      } else if constexpr (EPI == 2) {
        u16* Cu = (u16*)C;
        #pragma unroll
        for (int e = 0; e < 4; ++e) {
          float vv = acc[m][n][e] + bv;
          float gl = 0.5f * vv * (1.f + erff(vv * 0.70710678118f));
          Cu[coff + (long long)(rb + e) * ldc + c] = f2bf(gl);
        }
      } else {  // EPI == 3 : store V^T per head: vt[((b*8+h)*64+d)*TR + j]
        u16* Cu = (u16*)C;
        int b2 = rb / TR, j0 = rb - b2 * TR;
        int h2 = c >> 6, dd = c & 63;
        ushort4 pk;
        pk.x = f2bf(acc[m][n][0] + bv);
        pk.y = f2bf(acc[m][n][1] + bv);
        pk.z = f2bf(acc[m][n][2] + bv);
        pk.w = f2bf(acc[m][n][3] + bv);
        *(ushort4*)&Cu[(((size_t)b2 * 8 + h2) * 64 + dd) * TR + j0] = pk;
      }
    }
  }
}

// =============================== host ===============================
extern "C" void kernel_launch(void* const* d_in, const int* in_sizes, int n_in,
                              void* d_out, int out_size, void* d_ws, size_t ws_size,
                              hipStream_t stream) {
  const float* h_d = (const float*)d_in[0];
  const float* h_p = (const float*)d_in[1];
  const float* gd_w = (const float*)d_in[2];
  const float* gd_b = (const float*)d_in[3];
  const float* gp_w = (const float*)d_in[4];
  const float* gp_b = (const float*)d_in[5];
  const float* wqd_w = (const float*)d_in[6];  const float* wqd_b = (const float*)d_in[7];
  const float* wkp_w = (const float*)d_in[8];  const float* wkp_b = (const float*)d_in[9];
  const float* wvp_w = (const float*)d_in[10]; const float* wvp_b = (const float*)d_in[11];
  const float* wqp_w = (const float*)d_in[12]; const float* wqp_b = (const float*)d_in[13];
  const float* wkd_w = (const float*)d_in[14]; const float* wkd_b = (const float*)d_in[15];
  const float* wvd_w = (const float*)d_in[16]; const float* wvd_b = (const float*)d_in[17];
  const float* od_w = (const float*)d_in[18];  const float* od_b = (const float*)d_in[19];
  const float* op_w = (const float*)d_in[20];  const float* op_b = (const float*)d_in[21];
  const float* fd1_w = (const float*)d_in[22]; const float* fd1_b = (const float*)d_in[23];
  const float* fd2_w = (const float*)d_in[24]; const float* fd2_b = (const float*)d_in[25];
  const float* fp1_w = (const float*)d_in[26]; const float* fp1_b = (const float*)d_in[27];
  const float* fp2_w = (const float*)d_in[28]; const float* fp2_b = (const float*)d_in[29];
  const float* nd1_s = (const float*)d_in[30]; const float* nd1_b = (const float*)d_in[31];
  const float* nd2_s = (const float*)d_in[32]; const float* nd2_b = (const float*)d_in[33];
  const float* np1_s = (const float*)d_in[34]; const float* np1_b = (const float*)d_in[35];
  const float* np2_s = (const float*)d_in[36]; const float* np2_b = (const float*)d_in[37];
  const int* mask_d = (const int*)d_in[38];
  const int* mask_p = (const int*)d_in[39];

  constexpr int B = 16, Ld = 256, Lp = 1024, D = 512, H = 8, F = 2048;
  constexpr int Md = B * Ld;   // 4096
  constexpr int Mp = B * Lp;   // 16384
  constexpr int BH = B * H;    // 128

  char* ws = (char*)d_ws;
  size_t off = 0;
  auto alloc = [&](size_t bytes) {
    size_t o = off;
    off += (bytes + 255) & ~(size_t)255;
    return o;
  };
  auto a16 = [&](size_t els) { return (u16*)(ws + alloc(els * 2)); };
  auto a32 = [&](size_t els) { return (float*)(ws + alloc(els * 4)); };

  u16* w_qd = a16((size_t)D * D);
  u16* w_kp = a16((size_t)D * D);
  u16* w_vp = a16((size_t)D * D);
  u16* w_qp = a16((size_t)D * D);
  u16* w_kd = a16((size_t)D * D);
  u16* w_vd = a16((size_t)D * D);
  u16* w_od = a16((size_t)D * D);
  u16* w_op = a16((size_t)D * D);
  u16* w_fd1 = a16((size_t)F * D);
  u16* w_fd2 = a16((size_t)F * D);
  u16* w_fp1 = a16((size_t)F * D);
  u16* w_fp2 = a16((size_t)F * D);

  u16* hd16 = a16((size_t)Md * D);    // input h_d bf16, later attn1 out
  u16* hd2_16 = a16((size_t)Md * D);
  u16* hp16 = a16((size_t)Mp * D);    // input h_p bf16, later attn2 out / hp2 bf16
  u16* qd16 = a16((size_t)Md * D);    // qd, later kd
  u16* kp16 = a16((size_t)Mp * D);    // kp, later qp
  u16* vt16 = a16((size_t)Mp * D);    // vt1 [B,H,64,Lp]; later vt2 [B,H,64,Ld]
  float* obuf = a32((size_t)Mp * D);  // o-proj / ffn2 fp32 outputs (sequential)
  float* hd2 = a32((size_t)Md * D);
  float* hp2 = a32((size_t)Mp * D);
  u16* t16 = a16((size_t)Mp * F);     // ffn hidden (bf16, post-gelu)
  float* logg_d = a32(Md);
  float* logg_p = a32(Mp);

  // --- conversions (inputs + all weights) ---
  {
    const float* src[14] = {h_d, h_p, wqd_w, wkp_w, wvp_w, wqp_w, wkd_w,
                            wvd_w, od_w, op_w, fd1_w, fd2_w, fp1_w, fp2_w};
    u16* dst[14] = {hd16, hp16, w_qd, w_kp, w_vp, w_qp, w_kd,
                    w_vd, w_od, w_op, w_fd1, w_fd2, w_fp1, w_fp2};
    const int nn[14] = {Md * D, Mp * D, D * D, D * D, D * D, D * D, D * D,
                        D * D, D * D, D * D, F * D, F * D, F * D, F * D};
    for (int i = 0; i < 14; ++i)
      cvt_k<<<nn[i] / 1024, 256, 0, stream>>>(src[i], dst[i], nn[i]);
  }

  // --- gates (from ORIGINAL inputs) ---
  gate_k<<<Md / 4, 256, 0, stream>>>(h_d, gd_w, gd_b, logg_d);
  gate_k<<<Mp / 4, 256, 0, stream>>>(h_p, gp_w, gp_b, logg_p);

  // --- projections for attn1 ---
  gemm_k<2, 2, 2, 2, 1><<<dim3(D / 64, Md / 64, 1), 256, 0, stream>>>(
      hd16, w_qd, wqd_b, qd16, D, D, D, D, 0, 0, 0, 0, 0, 0, 0, 0, 0, 1, 0, 0);
  gemm_k<2, 2, 4, 4, 1><<<dim3(D / 128, Mp / 128, 1), 256, 0, stream>>>(
      hp16, w_kp, wkp_b, kp16, D, D, D, D, 0, 0, 0, 0, 0, 0, 0, 0, 0, 1, 0, 0);
  gemm_k<2, 2, 4, 4, 3><<<dim3(D / 128, Mp / 128, 1), 256, 0, stream>>>(
      hp16, w_vp, wvp_b, vt16, D, D, D, 0, 0, 0, 0, 0, 0, 0, 0, 0, 0, 1, 0, Lp);

  // --- attn1: drug attends protein (fused flash) ---
  flash_k<128><<<dim3(Ld / 64, 1, BH), 256, 0, stream>>>(
      qd16, kp16, vt16, logg_p, mask_p, hd16, Ld, Lp, 0.125f);

  // --- o-proj + LN1 -> h_d' ---
  gemm_k<2, 2, 2, 2, 0><<<dim3(D / 64, Md / 64, 1), 256, 0, stream>>>(
      hd16, w_od, od_b, obuf, D, D, D, D, 0, 0, 0, 0, 0, 0, 0, 0, 0, 1, 0, 0);
  ln_k<true><<<Md / 4, 256, 0, stream>>>(h_d, obuf, nd1_s, nd1_b, hd2, hd2_16);

  // --- projections for attn2 (K/V from UPDATED drug) ---
  gemm_k<2, 2, 4, 4, 1><<<dim3(D / 128, Mp / 128, 1), 256, 0, stream>>>(
      hp16, w_qp, wqp_b, kp16, D, D, D, D, 0, 0, 0, 0, 0, 0, 0, 0, 0, 1, 0, 0);
  gemm_k<2, 2, 2, 2, 1><<<dim3(D / 64, Md / 64, 1), 256, 0, stream>>>(
      hd2_16, w_kd, wkd_b, qd16, D, D, D, D, 0, 0, 0, 0, 0, 0, 0, 0, 0, 1, 0, 0);
  gemm_k<2, 2, 2, 2, 3><<<dim3(D / 64, Md / 64, 1), 256, 0, stream>>>(
      hd2_16, w_vd, wvd_b, vt16, D, D, D, 0, 0, 0, 0, 0, 0, 0, 0, 0, 0, 1, 0, Ld);

  // --- attn2: protein attends drug (fused flash) ---
  flash_k<128><<<dim3(Lp / 64, 1, BH), 256, 0, stream>>>(
      kp16, qd16, vt16, logg_d, mask_d, hp16, Lp, Ld, 0.125f);

  // --- o-proj + LN2 -> h_p' (bf16 into hp16 slot) ---
  gemm_k<2, 2, 4, 4, 0><<<dim3(D / 128, Mp / 128, 1), 256, 0, stream>>>(
      hp16, w_op, op_b, obuf, D, D, D, D, 0, 0, 0, 0, 0, 0, 0, 0, 0, 1, 0, 0);
  ln_k<true><<<Mp / 4, 256, 0, stream>>>(h_p, obuf, np1_s, np1_b, hp2, hp16);

  // --- FFN drug + final LN -> d_out[0 : Md*D] ---
  gemm_k<2, 2, 4, 4, 2><<<dim3(F / 128, Md / 128, 1), 256, 0, stream>>>(
      hd2_16, w_fd1, fd1_b, t16, D, D, D, F, 0, 0, 0, 0, 0, 0, 0, 0, 0, 1, 0, 0);
  gemm_k<2, 2, 2, 2, 0><<<dim3(D / 64, Md / 64, 1), 256, 0, stream>>>(
      t16, w_fd2, fd2_b, obuf, F, F, F, D, 0, 0, 0, 0, 0, 0, 0, 0, 0, 1, 0, 0);
  ln_k<false><<<Md / 4, 256, 0, stream>>>(hd2, obuf, nd2_s, nd2_b, (float*)d_out, nullptr);

  // --- FFN protein + final LN -> d_out[Md*D : ] ---
  gemm_k<2, 2, 4, 4, 2><<<dim3(F / 128, Mp / 128, 1), 256, 0, stream>>>(
      hp16, w_fp1, fp1_b, t16, D, D, D, F, 0, 0, 0, 0, 0, 0, 0, 0, 0, 1, 0, 0);
  gemm_k<2, 2, 4, 4, 0><<<dim3(D / 128, Mp / 128, 1), 256, 0, stream>>>(
      t16, w_fp2, fp2_b, obuf, F, F, F, D, 0, 0, 0, 0, 0, 0, 0, 0, 0, 1, 0, 0);
  ln_k<false><<<Mp / 4, 256, 0, stream>>>(hp2, obuf, np2_s, np2_b,
                                          (float*)d_out + (size_t)Md * D, nullptr);
}

// Round 3
// 406.565 us; speedup vs baseline: 2.4512x; 1.1059x over previous
//
#include <hip/hip_runtime.h>

typedef float f32x4 __attribute__((ext_vector_type(4)));
typedef short bfrag __attribute__((ext_vector_type(8)));
typedef short s16x8 __attribute__((ext_vector_type(8)));
typedef unsigned short u16;

__device__ __forceinline__ u16 f2bf(float f) {
  union { float f; unsigned u; } x; x.f = f;
  unsigned r = x.u + 0x7fffu + ((x.u >> 16) & 1u);
  return (u16)(r >> 16);
}
__device__ __forceinline__ float bf2f(u16 v) {
  union { unsigned u; float f; } x; x.u = ((unsigned)v) << 16;
  return x.f;
}

__device__ __forceinline__ void g2l16(const void* g, void* l) {
  void* gnc = const_cast<void*>(g);
  __builtin_amdgcn_global_load_lds((__attribute__((address_space(1))) void*)gnc,
                                   (__attribute__((address_space(3))) void*)l, 16, 0, 0);
}

__device__ __forceinline__ f32x4 mfma16(bfrag a, bfrag b, f32x4 c) {
  asm volatile("v_mfma_f32_16x16x32_bf16 %0, %1, %2, %0" : "+v"(c) : "v"(a), "v"(b));
  return c;
}

__device__ __forceinline__ float wred_sum(float s) {
  #pragma unroll
  for (int o = 32; o; o >>= 1) s += __shfl_xor(s, o);
  return s;
}

// ---------------- fused f32 -> bf16 convert (all 14 tensors, 1 launch) ----------------
struct CvtArgs {
  const float* s[14];
  u16* d[14];
  int eb[14];  // inclusive prefix of block counts
};

__global__ __launch_bounds__(256) void cvt_all(CvtArgs a) {
  const int blk = blockIdx.x;
  int base = 0;
  const float* sp = a.s[0];
  u16* dp = a.d[0];
  #pragma unroll
  for (int i = 0; i < 13; ++i) {
    if (blk >= a.eb[i]) { base = a.eb[i]; sp = a.s[i + 1]; dp = a.d[i + 1]; }
  }
  const size_t gi = ((size_t)(blk - base) * 256 + threadIdx.x) * 4;
  float4 f = *(const float4*)(sp + gi);
  ushort4 o;
  o.x = f2bf(f.x); o.y = f2bf(f.y); o.z = f2bf(f.z); o.w = f2bf(f.w);
  *(ushort4*)(dp + gi) = o;
}

// ---------------- uncertainty gates (both tensors, 1 launch) ----------------
__device__ __forceinline__ float softplus_s(float x) {
  return fmaxf(x, 0.f) + log1pf(expf(-fabsf(x)));
}

__global__ __launch_bounds__(256) void gate_k(
    const float* __restrict__ hd, const float* __restrict__ hp,
    const float* __restrict__ wd, const float* __restrict__ bd,
    const float* __restrict__ wp, const float* __restrict__ bp,
    float* __restrict__ lgd, float* __restrict__ lgp, int mdTok) {
  const int lane = threadIdx.x & 63, wv = threadIdx.x >> 6;
  size_t tok = (size_t)blockIdx.x * 4 + wv;
  const float* h; const float* w4; const float* b4; float* lg;
  if (tok < (size_t)mdTok) { h = hd; w4 = wd; b4 = bd; lg = lgd; }
  else { h = hp; w4 = wp; b4 = bp; lg = lgp; tok -= mdTok; }
  const float* x = h + tok * 512;
  float s0 = 0.f, s1 = 0.f, s2 = 0.f, s3 = 0.f;
  #pragma unroll
  for (int i = 0; i < 8; ++i) {
    int c = (i << 6) + lane;
    float xv = x[c];
    s0 += xv * w4[c];
    s1 += xv * w4[512 + c];
    s2 += xv * w4[1024 + c];
    s3 += xv * w4[1536 + c];
  }
  s0 = wred_sum(s0); s1 = wred_sum(s1); s2 = wred_sum(s2); s3 = wred_sum(s3);
  if (lane == 0) {
    float mu = s0 + b4[0];
    float va = softplus_s(s1 + b4[1]) + 1e-6f;
    float al = softplus_s(s2 + b4[2]) + 1.f + 1e-6f;
    float be = softplus_s(s3 + b4[3]) + 1e-6f;
    float se2 = be / (va * (al - 1.f));
    float g = (1.f / (1.f + expf(-mu))) * expf(-se2);
    g = fminf(fmaxf(g, 1e-3f), 1.f);
    lg[tok] = logf(g + 1e-9f);
  }
}

// ---------------- residual + LayerNorm (RES: 0=f32,1=bf16; OUT: 0=f32,1=bf16) ----------------
template <int RES, int OUT>
__global__ __launch_bounds__(256) void ln_k(const void* __restrict__ resv,
                                            const u16* __restrict__ y,
                                            const float* __restrict__ sc,
                                            const float* __restrict__ bi,
                                            void* __restrict__ outv) {
  const int lane = threadIdx.x & 63, w = threadIdx.x >> 6;
  const size_t row = (size_t)blockIdx.x * 4 + w;
  const int c0 = lane * 8;
  float v[8];
  s16x8 yv = *(const s16x8*)(y + row * 512 + c0);
  if constexpr (RES == 0) {
    const float* rf = (const float*)resv + row * 512 + c0;
    float4 r0 = *(const float4*)rf, r1 = *(const float4*)(rf + 4);
    v[0] = r0.x; v[1] = r0.y; v[2] = r0.z; v[3] = r0.w;
    v[4] = r1.x; v[5] = r1.y; v[6] = r1.z; v[7] = r1.w;
  } else {
    s16x8 rv = *(const s16x8*)((const u16*)resv + row * 512 + c0);
    #pragma unroll
    for (int i = 0; i < 8; ++i) v[i] = bf2f((u16)rv[i]);
  }
  float s = 0.f;
  #pragma unroll
  for (int i = 0; i < 8; ++i) { v[i] += bf2f((u16)yv[i]); s += v[i]; }
  s = wred_sum(s);
  float m = s * (1.f / 512.f);
  float s2 = 0.f;
  #pragma unroll
  for (int i = 0; i < 8; ++i) { float d = v[i] - m; s2 += d * d; }
  s2 = wred_sum(s2);
  float inv = rsqrtf(s2 * (1.f / 512.f) + 1e-5f);
  float4 sc0 = *(const float4*)(sc + c0), sc1 = *(const float4*)(sc + c0 + 4);
  float4 bi0 = *(const float4*)(bi + c0), bi1 = *(const float4*)(bi + c0 + 4);
  float scv[8] = {sc0.x, sc0.y, sc0.z, sc0.w, sc1.x, sc1.y, sc1.z, sc1.w};
  float biv[8] = {bi0.x, bi0.y, bi0.z, bi0.w, bi1.x, bi1.y, bi1.z, bi1.w};
  float o[8];
  #pragma unroll
  for (int i = 0; i < 8; ++i) o[i] = (v[i] - m) * inv * scv[i] + biv[i];
  if constexpr (OUT == 0) {
    float* of = (float*)outv + row * 512 + c0;
    *(float4*)of = float4{o[0], o[1], o[2], o[3]};
    *(float4*)(of + 4) = float4{o[4], o[5], o[6], o[7]};
  } else {
    s16x8 ov;
    #pragma unroll
    for (int i = 0; i < 8; ++i) ov[i] = (short)f2bf(o[i]);
    *(s16x8*)((u16*)outv + row * 512 + c0) = ov;
  }
}

// ---------------- fused flash cross-attention ----------------
template <int KT>
__global__ __launch_bounds__(256) void flash_k(
    const u16* __restrict__ Q, const u16* __restrict__ Kv,
    const u16* __restrict__ Vt, const float* __restrict__ logg,
    const int* __restrict__ mask, u16* __restrict__ Out,
    int Lq, int Lk, float scale) {
  __shared__ __align__(16) u16 Kl[KT * 64];
  __shared__ __align__(16) u16 Vl[64 * KT];
  __shared__ __align__(16) u16 Pl[64 * (KT + 8)];
  const int tid = threadIdx.x;
  const int lane = tid & 63, wv = tid >> 6;
  const int lr = lane & 15, lg4 = lane >> 4;
  const int bh = blockIdx.z;
  const int b = bh >> 3, h = bh & 7;
  const int q0 = blockIdx.x * 64;

  bfrag af[2];
  {
    const u16* qrow = Q + (size_t)(b * Lq + q0 + wv * 16 + lr) * 512 + h * 64;
    af[0] = *(const bfrag*)(qrow + lg4 * 8);
    af[1] = *(const bfrag*)(qrow + 32 + lg4 * 8);
  }
  float mreg[4] = {-3e38f, -3e38f, -3e38f, -3e38f};
  float lreg[4] = {0.f, 0.f, 0.f, 0.f};
  f32x4 Oa[4] = {};
  const float* lgb = logg + (size_t)b * Lk;
  const int* mkb = mask + (size_t)b * Lk;

  const int NKT = Lk / KT;
  for (int t = 0; t < NKT; ++t) {
    const int k0 = t * KT;
    __syncthreads();
    {
      const char* kb = (const char*)(Kv + (size_t)(b * Lk + k0) * 512 + h * 64);
      #pragma unroll
      for (int r = 0; r < KT / 32; ++r) {
        int o = r * 4096 + tid * 16;
        int rr = o >> 7, cd = (o >> 4) & 7;
        int cs = cd ^ (rr & 7);
        g2l16(kb + (size_t)rr * 1024 + cs * 16, (char*)Kl + o);
      }
      const char* vb = (const char*)(Vt + (size_t)bh * 64 * Lk + k0);
      #pragma unroll
      for (int r = 0; r < KT / 32; ++r) {
        int o = r * 4096 + tid * 16;
        int rr = o >> 8, cd = (o >> 4) & 15;
        int cs = (cd & 8) | ((cd & 7) ^ (rr & 7));
        g2l16(vb + (size_t)rr * (Lk * 2) + cs * 16, (char*)Vl + o);
      }
    }
    __syncthreads();

    f32x4 sa[KT / 16];
    #pragma unroll
    for (int n = 0; n < KT / 16; ++n) {
      sa[n] = f32x4{0.f, 0.f, 0.f, 0.f};
      int row = n * 16 + lr;
      #pragma unroll
      for (int ks = 0; ks < 2; ++ks) {
        bfrag kf = *(const bfrag*)(Kl + row * 64 + (((ks * 4 + lg4) ^ (row & 7)) * 8));
        sa[n] = mfma16(af[ks], kf, sa[n]);
      }
    }
    asm volatile("s_nop 7\n\ts_nop 7");

    float pv[KT / 16][4];
    float nm[4] = {-3e38f, -3e38f, -3e38f, -3e38f};
    #pragma unroll
    for (int n = 0; n < KT / 16; ++n) {
      int kk = k0 + n * 16 + lr;
      float lgv = lgb[kk];
      int mkv = mkb[kk];
      #pragma unroll
      for (int e = 0; e < 4; ++e) {
        float tv = mkv ? fmaf(sa[n][e], scale, lgv) : -1e9f;
        pv[n][e] = tv;
        nm[e] = fmaxf(nm[e], tv);
      }
    }
    float fac[4], rs[4];
    #pragma unroll
    for (int e = 0; e < 4; ++e) {
      nm[e] = fmaxf(nm[e], __shfl_xor(nm[e], 1));
      nm[e] = fmaxf(nm[e], __shfl_xor(nm[e], 2));
      nm[e] = fmaxf(nm[e], __shfl_xor(nm[e], 4));
      nm[e] = fmaxf(nm[e], __shfl_xor(nm[e], 8));
      nm[e] = fmaxf(nm[e], mreg[e]);
      fac[e] = __expf(mreg[e] - nm[e]);
      mreg[e] = nm[e];
      rs[e] = 0.f;
    }
    #pragma unroll
    for (int n = 0; n < KT / 16; ++n)
      #pragma unroll
      for (int e = 0; e < 4; ++e) {
        float p = __expf(pv[n][e] - nm[e]);
        pv[n][e] = p;
        rs[e] += p;
      }
    #pragma unroll
    for (int e = 0; e < 4; ++e) {
      rs[e] += __shfl_xor(rs[e], 1);
      rs[e] += __shfl_xor(rs[e], 2);
      rs[e] += __shfl_xor(rs[e], 4);
      rs[e] += __shfl_xor(rs[e], 8);
      lreg[e] = lreg[e] * fac[e] + rs[e];
    }
    #pragma unroll
    for (int n2 = 0; n2 < 4; ++n2)
      #pragma unroll
      for (int e = 0; e < 4; ++e) Oa[n2][e] *= fac[e];

    {
      int prow = wv * 16 + lg4 * 4;
      #pragma unroll
      for (int n = 0; n < KT / 16; ++n)
        #pragma unroll
        for (int e = 0; e < 4; ++e)
          Pl[(prow + e) * (KT + 8) + n * 16 + lr] = f2bf(pv[n][e]);
    }
    #pragma unroll
    for (int ks = 0; ks < KT / 32; ++ks) {
      bfrag pf = *(const bfrag*)(Pl + (wv * 16 + lr) * (KT + 8) + (ks * 4 + lg4) * 8);
      #pragma unroll
      for (int n2 = 0; n2 < 4; ++n2) {
        int vrow = n2 * 16 + lr;
        int ch = ks * 4 + lg4;
        int chs = (ch & 8) | ((ch & 7) ^ (vrow & 7));
        bfrag vf = *(const bfrag*)(Vl + vrow * KT + chs * 8);
        Oa[n2] = mfma16(pf, vf, Oa[n2]);
      }
    }
  }
  asm volatile("s_nop 7\n\ts_nop 7");

  float inv[4];
  #pragma unroll
  for (int e = 0; e < 4; ++e) inv[e] = 1.f / lreg[e];
  u16* ob = Out + (size_t)(b * Lq + q0 + wv * 16 + lg4 * 4) * 512 + h * 64;
  #pragma unroll
  for (int n2 = 0; n2 < 4; ++n2)
    #pragma unroll
    for (int e = 0; e < 4; ++e)
      ob[(size_t)e * 512 + n2 * 16 + lr] = f2bf(Oa[n2][e] * inv[e]);
}

// ---------------- pipelined MFMA GEMM: C[m,n] = sum_k A[m,k]*W[n,k] (+bias) ----------------
// 128x128 tile, 4 waves, BK=64, double-buffered LDS, single barrier per K-step,
// stage(t+1) issued BEFORE compute(t). XCD-bijective block swizzle, column-major decomp.
// EPI: 1=bf16 store, 2=gelu->bf16, 3=per-head transposed V store ->bf16
template <int FM, int FN, int EPI>
__global__ __launch_bounds__(256) void gemm_k(
    const u16* __restrict__ A, const u16* __restrict__ W,
    const float* __restrict__ bias, void* __restrict__ C,
    int K, int lda, int ldw, int ldc, int MB, int TR) {
  constexpr int BM = 2 * FM * 16;
  constexpr int BN = 2 * FN * 16;
  __shared__ __align__(16) u16 Al[2][BM * 64];
  __shared__ __align__(16) u16 Wl[2][BN * 64];
  const int tid = threadIdx.x;
  // bijective XCD swizzle (all grids are multiples of 8), column-major decomp
  const int qq = gridDim.x >> 3;
  const int wg = (blockIdx.x & 7) * qq + (blockIdx.x >> 3);
  const int by = wg % MB, bx = wg / MB;
  const int row0 = by * BM, col0 = bx * BN;
  const int lane = tid & 63, wv = tid >> 6;
  const int wr = wv >> 1, wc = wv & 1;
  const int rowW = wr * FM * 16, colW = wc * FN * 16;
  const int lr = lane & 15, lg4 = lane >> 4;

  f32x4 acc[FM][FN] = {};
  const int NT = K >> 6;

  auto stage = [&](int bsel, int k0) {
    #pragma unroll
    for (int r = 0; r < BM / 32; ++r) {
      int o = r * 4096 + tid * 16;
      int arow = o >> 7, cd = (o >> 4) & 7, cs = cd ^ (arow & 7);
      g2l16((const char*)(A + (size_t)(row0 + arow) * lda + k0) + cs * 16,
            (char*)Al[bsel] + o);
    }
    #pragma unroll
    for (int r = 0; r < BN / 32; ++r) {
      int o = r * 4096 + tid * 16;
      int wrow = o >> 7, cd = (o >> 4) & 7, cs = cd ^ (wrow & 7);
      g2l16((const char*)(W + (size_t)(col0 + wrow) * ldw + k0) + cs * 16,
            (char*)Wl[bsel] + o);
    }
  };

  auto body = [&](int cur, int t) {
    if (t + 1 < NT) stage(cur ^ 1, (t + 1) << 6);
    bfrag af[FM][2], wf[FN][2];
    #pragma unroll
    for (int m = 0; m < FM; ++m) {
      int rowi = rowW + m * 16 + lr;
      #pragma unroll
      for (int ks = 0; ks < 2; ++ks)
        af[m][ks] =
            *(const bfrag*)(Al[cur] + rowi * 64 + (((ks * 4 + lg4) ^ (rowi & 7)) * 8));
    }
    #pragma unroll
    for (int n = 0; n < FN; ++n) {
      int rowi = colW + n * 16 + lr;
      #pragma unroll
      for (int ks = 0; ks < 2; ++ks)
        wf[n][ks] =
            *(const bfrag*)(Wl[cur] + rowi * 64 + (((ks * 4 + lg4) ^ (rowi & 7)) * 8));
    }
    #pragma unroll
    for (int m = 0; m < FM; ++m)
      #pragma unroll
      for (int n = 0; n < FN; ++n) {
        acc[m][n] = mfma16(af[m][0], wf[n][0], acc[m][n]);
        acc[m][n] = mfma16(af[m][1], wf[n][1], acc[m][n]);
      }
    __syncthreads();
  };

  stage(0, 0);
  __syncthreads();
  for (int t = 0; t < NT; t += 2) {
    body(0, t);
    body(1, t + 1);
  }
  asm volatile("s_nop 7\n\ts_nop 7\n\ts_nop 7");

  #pragma unroll
  for (int m = 0; m < FM; ++m) {
    #pragma unroll
    for (int n = 0; n < FN; ++n) {
      int rb = row0 + rowW + m * 16 + lg4 * 4;
      int c = col0 + colW + n * 16 + lr;
      float bv = bias[c];
      if constexpr (EPI == 1) {
        u16* Cu = (u16*)C;
        #pragma unroll
        for (int e = 0; e < 4; ++e)
          Cu[(size_t)(rb + e) * ldc + c] = f2bf(acc[m][n][e] + bv);
      } else if constexpr (EPI == 2) {
        u16* Cu = (u16*)C;
        #pragma unroll
        for (int e = 0; e < 4; ++e) {
          float vv = acc[m][n][e] + bv;
          float gl = 0.5f * vv * (1.f + erff(vv * 0.70710678118f));
          Cu[(size_t)(rb + e) * ldc + c] = f2bf(gl);
        }
      } else {  // EPI == 3 : vt[((b*8+h)*64+d)*TR + j]
        u16* Cu = (u16*)C;
        int b2 = rb / TR, j0 = rb - b2 * TR;
        int h2 = c >> 6, dd = c & 63;
        ushort4 pk;
        pk.x = f2bf(acc[m][n][0] + bv);
        pk.y = f2bf(acc[m][n][1] + bv);
        pk.z = f2bf(acc[m][n][2] + bv);
        pk.w = f2bf(acc[m][n][3] + bv);
        *(ushort4*)&Cu[(((size_t)b2 * 8 + h2) * 64 + dd) * TR + j0] = pk;
      }
    }
  }
}

// =============================== host ===============================
extern "C" void kernel_launch(void* const* d_in, const int* in_sizes, int n_in,
                              void* d_out, int out_size, void* d_ws, size_t ws_size,
                              hipStream_t stream) {
  const float* h_d = (const float*)d_in[0];
  const float* h_p = (const float*)d_in[1];
  const float* gd_w = (const float*)d_in[2];
  const float* gd_b = (const float*)d_in[3];
  const float* gp_w = (const float*)d_in[4];
  const float* gp_b = (const float*)d_in[5];
  const float* wqd_w = (const float*)d_in[6];  const float* wqd_b = (const float*)d_in[7];
  const float* wkp_w = (const float*)d_in[8];  const float* wkp_b = (const float*)d_in[9];
  const float* wvp_w = (const float*)d_in[10]; const float* wvp_b = (const float*)d_in[11];
  const float* wqp_w = (const float*)d_in[12]; const float* wqp_b = (const float*)d_in[13];
  const float* wkd_w = (const float*)d_in[14]; const float* wkd_b = (const float*)d_in[15];
  const float* wvd_w = (const float*)d_in[16]; const float* wvd_b = (const float*)d_in[17];
  const float* od_w = (const float*)d_in[18];  const float* od_b = (const float*)d_in[19];
  const float* op_w = (const float*)d_in[20];  const float* op_b = (const float*)d_in[21];
  const float* fd1_w = (const float*)d_in[22]; const float* fd1_b = (const float*)d_in[23];
  const float* fd2_w = (const float*)d_in[24]; const float* fd2_b = (const float*)d_in[25];
  const float* fp1_w = (const float*)d_in[26]; const float* fp1_b = (const float*)d_in[27];
  const float* fp2_w = (const float*)d_in[28]; const float* fp2_b = (const float*)d_in[29];
  const float* nd1_s = (const float*)d_in[30]; const float* nd1_b = (const float*)d_in[31];
  const float* nd2_s = (const float*)d_in[32]; const float* nd2_b = (const float*)d_in[33];
  const float* np1_s = (const float*)d_in[34]; const float* np1_b = (const float*)d_in[35];
  const float* np2_s = (const float*)d_in[36]; const float* np2_b = (const float*)d_in[37];
  const int* mask_d = (const int*)d_in[38];
  const int* mask_p = (const int*)d_in[39];

  constexpr int B = 16, Ld = 256, Lp = 1024, D = 512, H = 8, F = 2048;
  constexpr int Md = B * Ld;   // 4096
  constexpr int Mp = B * Lp;   // 16384
  constexpr int BH = B * H;    // 128

  char* ws = (char*)d_ws;
  size_t off = 0;
  auto alloc = [&](size_t bytes) {
    size_t o = off;
    off += (bytes + 255) & ~(size_t)255;
    return o;
  };
  auto a16 = [&](size_t els) { return (u16*)(ws + alloc(els * 2)); };
  auto a32 = [&](size_t els) { return (float*)(ws + alloc(els * 4)); };

  u16* w_qd = a16((size_t)D * D);
  u16* w_kp = a16((size_t)D * D);
  u16* w_vp = a16((size_t)D * D);
  u16* w_qp = a16((size_t)D * D);
  u16* w_kd = a16((size_t)D * D);
  u16* w_vd = a16((size_t)D * D);
  u16* w_od = a16((size_t)D * D);
  u16* w_op = a16((size_t)D * D);
  u16* w_fd1 = a16((size_t)F * D);
  u16* w_fd2 = a16((size_t)F * D);
  u16* w_fp1 = a16((size_t)F * D);
  u16* w_fp2 = a16((size_t)F * D);

  u16* hd16 = a16((size_t)Md * D);     // h_d bf16 -> attn1 out
  u16* hd2_16 = a16((size_t)Md * D);   // h_d' (post LN1), residual for final LN
  u16* hp16 = a16((size_t)Mp * D);     // h_p bf16 -> attn2 out -> h_p'
  u16* qd16 = a16((size_t)Md * D);     // qd -> kd
  u16* kp16 = a16((size_t)Mp * D);     // kp -> qp
  u16* vt16 = a16((size_t)Mp * D);     // vp^T -> vd^T
  u16* obuf16 = a16((size_t)Mp * D);   // o-proj / ffn2 outputs (sequential lifetimes)
  u16* t16 = a16((size_t)Mp * F);      // ffn hidden (post-gelu)
  float* logg_d = a32(Md);
  float* logg_p = a32(Mp);

  // --- fused conversions (2 inputs + 12 weights) ---
  {
    CvtArgs a;
    const float* src[14] = {h_d, h_p, wqd_w, wkp_w, wvp_w, wqp_w, wkd_w,
                            wvd_w, od_w, op_w, fd1_w, fd2_w, fp1_w, fp2_w};
    u16* dst[14] = {hd16, hp16, w_qd, w_kp, w_vp, w_qp, w_kd,
                    w_vd, w_od, w_op, w_fd1, w_fd2, w_fp1, w_fp2};
    const int nelem[14] = {Md * D, Mp * D, D * D, D * D, D * D, D * D, D * D,
                           D * D, D * D, D * D, F * D, F * D, F * D, F * D};
    int pfx = 0;
    for (int i = 0; i < 14; ++i) {
      a.s[i] = src[i];
      a.d[i] = dst[i];
      pfx += nelem[i] / 1024;
      a.eb[i] = pfx;
    }
    cvt_all<<<pfx, 256, 0, stream>>>(a);
  }

  // --- gates (from ORIGINAL inputs) ---
  gate_k<<<(Md + Mp) / 4, 256, 0, stream>>>(h_d, h_p, gd_w, gd_b, gp_w, gp_b,
                                            logg_d, logg_p, Md);

  // --- projections for attn1 ---
  gemm_k<4, 4, 1><<<(Md / 128) * (D / 128), 256, 0, stream>>>(
      hd16, w_qd, wqd_b, qd16, D, D, D, D, Md / 128, 0);
  gemm_k<4, 4, 1><<<(Mp / 128) * (D / 128), 256, 0, stream>>>(
      hp16, w_kp, wkp_b, kp16, D, D, D, D, Mp / 128, 0);
  gemm_k<4, 4, 3><<<(Mp / 128) * (D / 128), 256, 0, stream>>>(
      hp16, w_vp, wvp_b, vt16, D, D, D, 0, Mp / 128, Lp);

  // --- attn1: drug attends protein ---
  flash_k<128><<<dim3(Ld / 64, 1, BH), 256, 0, stream>>>(
      qd16, kp16, vt16, logg_p, mask_p, hd16, Ld, Lp, 0.125f);

  // --- o-proj + LN1 -> h_d' (bf16) ---
  gemm_k<4, 4, 1><<<(Md / 128) * (D / 128), 256, 0, stream>>>(
      hd16, w_od, od_b, obuf16, D, D, D, D, Md / 128, 0);
  ln_k<0, 1><<<Md / 4, 256, 0, stream>>>(h_d, obuf16, nd1_s, nd1_b, hd2_16);

  // --- projections for attn2 (K/V from UPDATED drug) ---
  gemm_k<4, 4, 1><<<(Mp / 128) * (D / 128), 256, 0, stream>>>(
      hp16, w_qp, wqp_b, kp16, D, D, D, D, Mp / 128, 0);
  gemm_k<4, 4, 1><<<(Md / 128) * (D / 128), 256, 0, stream>>>(
      hd2_16, w_kd, wkd_b, qd16, D, D, D, D, Md / 128, 0);
  gemm_k<4, 4, 3><<<(Md / 128) * (D / 128), 256, 0, stream>>>(
      hd2_16, w_vd, wvd_b, vt16, D, D, D, 0, Md / 128, Ld);

  // --- attn2: protein attends drug ---
  flash_k<128><<<dim3(Lp / 64, 1, BH), 256, 0, stream>>>(
      kp16, qd16, vt16, logg_d, mask_d, hp16, Lp, Ld, 0.125f);

  // --- o-proj + LN2 -> h_p' (bf16, into hp16) ---
  gemm_k<4, 4, 1><<<(Mp / 128) * (D / 128), 256, 0, stream>>>(
      hp16, w_op, op_b, obuf16, D, D, D, D, Mp / 128, 0);
  ln_k<0, 1><<<Mp / 4, 256, 0, stream>>>(h_p, obuf16, np1_s, np1_b, hp16);

  // --- FFN drug + final LN -> d_out[0 : Md*D] ---
  gemm_k<4, 4, 2><<<(Md / 128) * (F / 128), 256, 0, stream>>>(
      hd2_16, w_fd1, fd1_b, t16, D, D, D, F, Md / 128, 0);
  gemm_k<4, 4, 1><<<(Md / 128) * (D / 128), 256, 0, stream>>>(
      t16, w_fd2, fd2_b, obuf16, F, F, F, D, Md / 128, 0);
  ln_k<1, 0><<<Md / 4, 256, 0, stream>>>(hd2_16, obuf16, nd2_s, nd2_b, (float*)d_out);

  // --- FFN protein + final LN -> d_out[Md*D : ] ---
  gemm_k<4, 4, 2><<<(Mp / 128) * (F / 128), 256, 0, stream>>>(
      hp16, w_fp1, fp1_b, t16, D, D, D, F, Mp / 128, 0);
  gemm_k<4, 4, 1><<<(Mp / 128) * (D / 128), 256, 0, stream>>>(
      t16, w_fp2, fp2_b, obuf16, F, F, F, D, Mp / 128, 0);
  ln_k<1, 0><<<Mp / 4, 256, 0, stream>>>(hp16, obuf16, np2_s, np2_b,
                                         (float*)d_out + (size_t)Md * D);
}

// Round 4
// 394.502 us; speedup vs baseline: 2.5262x; 1.0306x over previous
//
#include <hip/hip_runtime.h>

typedef float f32x4 __attribute__((ext_vector_type(4)));
typedef short bfrag __attribute__((ext_vector_type(8)));
typedef short s16x8 __attribute__((ext_vector_type(8)));
typedef unsigned short u16;

__device__ __forceinline__ u16 f2bf(float f) {
  union { float f; unsigned u; } x; x.f = f;
  unsigned r = x.u + 0x7fffu + ((x.u >> 16) & 1u);
  return (u16)(r >> 16);
}
__device__ __forceinline__ float bf2f(u16 v) {
  union { unsigned u; float f; } x; x.u = ((unsigned)v) << 16;
  return x.f;
}

__device__ __forceinline__ void g2l16(const void* g, void* l) {
  void* gnc = const_cast<void*>(g);
  __builtin_amdgcn_global_load_lds((__attribute__((address_space(1))) void*)gnc,
                                   (__attribute__((address_space(3))) void*)l, 16, 0, 0);
}

__device__ __forceinline__ f32x4 mfma16(bfrag a, bfrag b, f32x4 c) {
  asm volatile("v_mfma_f32_16x16x32_bf16 %0, %1, %2, %0" : "+v"(c) : "v"(a), "v"(b));
  return c;
}

__device__ __forceinline__ float wred_sum(float s) {
  #pragma unroll
  for (int o = 32; o; o >>= 1) s += __shfl_xor(s, o);
  return s;
}

// ---------------- fused f32 -> bf16 convert (all 14 tensors, 1 launch) ----------------
struct CvtArgs {
  const float* s[14];
  u16* d[14];
  int eb[14];  // inclusive prefix of block counts
};

__global__ __launch_bounds__(256) void cvt_all(CvtArgs a) {
  const int blk = blockIdx.x;
  int base = 0;
  const float* sp = a.s[0];
  u16* dp = a.d[0];
  #pragma unroll
  for (int i = 0; i < 13; ++i) {
    if (blk >= a.eb[i]) { base = a.eb[i]; sp = a.s[i + 1]; dp = a.d[i + 1]; }
  }
  const size_t gi = ((size_t)(blk - base) * 256 + threadIdx.x) * 4;
  float4 f = *(const float4*)(sp + gi);
  ushort4 o;
  o.x = f2bf(f.x); o.y = f2bf(f.y); o.z = f2bf(f.z); o.w = f2bf(f.w);
  *(ushort4*)(dp + gi) = o;
}

// ---------------- uncertainty gates (both tensors, 1 launch) ----------------
__device__ __forceinline__ float softplus_s(float x) {
  return fmaxf(x, 0.f) + log1pf(expf(-fabsf(x)));
}

__global__ __launch_bounds__(256) void gate_k(
    const float* __restrict__ hd, const float* __restrict__ hp,
    const float* __restrict__ wd, const float* __restrict__ bd,
    const float* __restrict__ wp, const float* __restrict__ bp,
    float* __restrict__ lgd, float* __restrict__ lgp, int mdTok) {
  const int lane = threadIdx.x & 63, wv = threadIdx.x >> 6;
  size_t tok = (size_t)blockIdx.x * 4 + wv;
  const float* h; const float* w4; const float* b4; float* lg;
  if (tok < (size_t)mdTok) { h = hd; w4 = wd; b4 = bd; lg = lgd; }
  else { h = hp; w4 = wp; b4 = bp; lg = lgp; tok -= mdTok; }
  const float* x = h + tok * 512;
  float s0 = 0.f, s1 = 0.f, s2 = 0.f, s3 = 0.f;
  #pragma unroll
  for (int i = 0; i < 8; ++i) {
    int c = (i << 6) + lane;
    float xv = x[c];
    s0 += xv * w4[c];
    s1 += xv * w4[512 + c];
    s2 += xv * w4[1024 + c];
    s3 += xv * w4[1536 + c];
  }
  s0 = wred_sum(s0); s1 = wred_sum(s1); s2 = wred_sum(s2); s3 = wred_sum(s3);
  if (lane == 0) {
    float mu = s0 + b4[0];
    float va = softplus_s(s1 + b4[1]) + 1e-6f;
    float al = softplus_s(s2 + b4[2]) + 1.f + 1e-6f;
    float be = softplus_s(s3 + b4[3]) + 1e-6f;
    float se2 = be / (va * (al - 1.f));
    float g = (1.f / (1.f + expf(-mu))) * expf(-se2);
    g = fminf(fmaxf(g, 1e-3f), 1.f);
    lg[tok] = logf(g + 1e-9f);
  }
}

// ---------------- residual + LayerNorm (RES: 0=f32,1=bf16; OUT: 0=f32,1=bf16) ----------------
template <int RES, int OUT>
__global__ __launch_bounds__(256) void ln_k(const void* __restrict__ resv,
                                            const u16* __restrict__ y,
                                            const float* __restrict__ sc,
                                            const float* __restrict__ bi,
                                            void* __restrict__ outv) {
  const int lane = threadIdx.x & 63, w = threadIdx.x >> 6;
  const size_t row = (size_t)blockIdx.x * 4 + w;
  const int c0 = lane * 8;
  float v[8];
  s16x8 yv = *(const s16x8*)(y + row * 512 + c0);
  if constexpr (RES == 0) {
    const float* rf = (const float*)resv + row * 512 + c0;
    float4 r0 = *(const float4*)rf, r1 = *(const float4*)(rf + 4);
    v[0] = r0.x; v[1] = r0.y; v[2] = r0.z; v[3] = r0.w;
    v[4] = r1.x; v[5] = r1.y; v[6] = r1.z; v[7] = r1.w;
  } else {
    s16x8 rv = *(const s16x8*)((const u16*)resv + row * 512 + c0);
    #pragma unroll
    for (int i = 0; i < 8; ++i) v[i] = bf2f((u16)rv[i]);
  }
  float s = 0.f;
  #pragma unroll
  for (int i = 0; i < 8; ++i) { v[i] += bf2f((u16)yv[i]); s += v[i]; }
  s = wred_sum(s);
  float m = s * (1.f / 512.f);
  float s2 = 0.f;
  #pragma unroll
  for (int i = 0; i < 8; ++i) { float d = v[i] - m; s2 += d * d; }
  s2 = wred_sum(s2);
  float inv = rsqrtf(s2 * (1.f / 512.f) + 1e-5f);
  float4 sc0 = *(const float4*)(sc + c0), sc1 = *(const float4*)(sc + c0 + 4);
  float4 bi0 = *(const float4*)(bi + c0), bi1 = *(const float4*)(bi + c0 + 4);
  float scv[8] = {sc0.x, sc0.y, sc0.z, sc0.w, sc1.x, sc1.y, sc1.z, sc1.w};
  float biv[8] = {bi0.x, bi0.y, bi0.z, bi0.w, bi1.x, bi1.y, bi1.z, bi1.w};
  float o[8];
  #pragma unroll
  for (int i = 0; i < 8; ++i) o[i] = (v[i] - m) * inv * scv[i] + biv[i];
  if constexpr (OUT == 0) {
    float* of = (float*)outv + row * 512 + c0;
    *(float4*)of = float4{o[0], o[1], o[2], o[3]};
    *(float4*)(of + 4) = float4{o[4], o[5], o[6], o[7]};
  } else {
    s16x8 ov;
    #pragma unroll
    for (int i = 0; i < 8; ++i) ov[i] = (short)f2bf(o[i]);
    *(s16x8*)((u16*)outv + row * 512 + c0) = ov;
  }
}

// ---------------- fused flash cross-attention ----------------
template <int KT>
__global__ __launch_bounds__(256) void flash_k(
    const u16* __restrict__ Q, const u16* __restrict__ Kv,
    const u16* __restrict__ Vt, const float* __restrict__ logg,
    const int* __restrict__ mask, u16* __restrict__ Out,
    int Lq, int Lk, float scale) {
  __shared__ __align__(16) u16 Kl[KT * 64];
  __shared__ __align__(16) u16 Vl[64 * KT];
  __shared__ __align__(16) u16 Pl[64 * (KT + 8)];
  const int tid = threadIdx.x;
  const int lane = tid & 63, wv = tid >> 6;
  const int lr = lane & 15, lg4 = lane >> 4;
  const int bh = blockIdx.z;
  const int b = bh >> 3, h = bh & 7;
  const int q0 = blockIdx.x * 64;

  bfrag af[2];
  {
    const u16* qrow = Q + (size_t)(b * Lq + q0 + wv * 16 + lr) * 512 + h * 64;
    af[0] = *(const bfrag*)(qrow + lg4 * 8);
    af[1] = *(const bfrag*)(qrow + 32 + lg4 * 8);
  }
  float mreg[4] = {-3e38f, -3e38f, -3e38f, -3e38f};
  float lreg[4] = {0.f, 0.f, 0.f, 0.f};
  f32x4 Oa[4] = {};
  const float* lgb = logg + (size_t)b * Lk;
  const int* mkb = mask + (size_t)b * Lk;

  const int NKT = Lk / KT;
  for (int t = 0; t < NKT; ++t) {
    const int k0 = t * KT;
    __syncthreads();
    {
      const char* kb = (const char*)(Kv + (size_t)(b * Lk + k0) * 512 + h * 64);
      #pragma unroll
      for (int r = 0; r < KT / 32; ++r) {
        int o = r * 4096 + tid * 16;
        int rr = o >> 7, cd = (o >> 4) & 7;
        int cs = cd ^ (rr & 7);
        g2l16(kb + (size_t)rr * 1024 + cs * 16, (char*)Kl + o);
      }
      const char* vb = (const char*)(Vt + (size_t)bh * 64 * Lk + k0);
      #pragma unroll
      for (int r = 0; r < KT / 32; ++r) {
        int o = r * 4096 + tid * 16;
        int rr = o >> 8, cd = (o >> 4) & 15;
        int cs = (cd & 8) | ((cd & 7) ^ (rr & 7));
        g2l16(vb + (size_t)rr * (Lk * 2) + cs * 16, (char*)Vl + o);
      }
    }
    __syncthreads();

    f32x4 sa[KT / 16];
    #pragma unroll
    for (int n = 0; n < KT / 16; ++n) {
      sa[n] = f32x4{0.f, 0.f, 0.f, 0.f};
      int row = n * 16 + lr;
      #pragma unroll
      for (int ks = 0; ks < 2; ++ks) {
        bfrag kf = *(const bfrag*)(Kl + row * 64 + (((ks * 4 + lg4) ^ (row & 7)) * 8));
        sa[n] = mfma16(af[ks], kf, sa[n]);
      }
    }
    asm volatile("s_nop 7\n\ts_nop 7");

    float pv[KT / 16][4];
    float nm[4] = {-3e38f, -3e38f, -3e38f, -3e38f};
    #pragma unroll
    for (int n = 0; n < KT / 16; ++n) {
      int kk = k0 + n * 16 + lr;
      float lgv = lgb[kk];
      int mkv = mkb[kk];
      #pragma unroll
      for (int e = 0; e < 4; ++e) {
        float tv = mkv ? fmaf(sa[n][e], scale, lgv) : -1e9f;
        pv[n][e] = tv;
        nm[e] = fmaxf(nm[e], tv);
      }
    }
    float fac[4], rs[4];
    #pragma unroll
    for (int e = 0; e < 4; ++e) {
      nm[e] = fmaxf(nm[e], __shfl_xor(nm[e], 1));
      nm[e] = fmaxf(nm[e], __shfl_xor(nm[e], 2));
      nm[e] = fmaxf(nm[e], __shfl_xor(nm[e], 4));
      nm[e] = fmaxf(nm[e], __shfl_xor(nm[e], 8));
      nm[e] = fmaxf(nm[e], mreg[e]);
      fac[e] = __expf(mreg[e] - nm[e]);
      mreg[e] = nm[e];
      rs[e] = 0.f;
    }
    #pragma unroll
    for (int n = 0; n < KT / 16; ++n)
      #pragma unroll
      for (int e = 0; e < 4; ++e) {
        float p = __expf(pv[n][e] - nm[e]);
        pv[n][e] = p;
        rs[e] += p;
      }
    #pragma unroll
    for (int e = 0; e < 4; ++e) {
      rs[e] += __shfl_xor(rs[e], 1);
      rs[e] += __shfl_xor(rs[e], 2);
      rs[e] += __shfl_xor(rs[e], 4);
      rs[e] += __shfl_xor(rs[e], 8);
      lreg[e] = lreg[e] * fac[e] + rs[e];
    }
    #pragma unroll
    for (int n2 = 0; n2 < 4; ++n2)
      #pragma unroll
      for (int e = 0; e < 4; ++e) Oa[n2][e] *= fac[e];

    {
      int prow = wv * 16 + lg4 * 4;
      #pragma unroll
      for (int n = 0; n < KT / 16; ++n)
        #pragma unroll
        for (int e = 0; e < 4; ++e)
          Pl[(prow + e) * (KT + 8) + n * 16 + lr] = f2bf(pv[n][e]);
    }
    #pragma unroll
    for (int ks = 0; ks < KT / 32; ++ks) {
      bfrag pf = *(const bfrag*)(Pl + (wv * 16 + lr) * (KT + 8) + (ks * 4 + lg4) * 8);
      #pragma unroll
      for (int n2 = 0; n2 < 4; ++n2) {
        int vrow = n2 * 16 + lr;
        int ch = ks * 4 + lg4;
        int chs = (ch & 8) | ((ch & 7) ^ (vrow & 7));
        bfrag vf = *(const bfrag*)(Vl + vrow * KT + chs * 8);
        Oa[n2] = mfma16(pf, vf, Oa[n2]);
      }
    }
  }
  asm volatile("s_nop 7\n\ts_nop 7");

  float inv[4];
  #pragma unroll
  for (int e = 0; e < 4; ++e) inv[e] = 1.f / lreg[e];
  u16* ob = Out + (size_t)(b * Lq + q0 + wv * 16 + lg4 * 4) * 512 + h * 64;
  #pragma unroll
  for (int n2 = 0; n2 < 4; ++n2)
    #pragma unroll
    for (int e = 0; e < 4; ++e)
      ob[(size_t)e * 512 + n2 * 16 + lr] = f2bf(Oa[n2][e] * inv[e]);
}

// ---------------- counted-vmcnt pipelined MFMA GEMM ----------------
// C[m,n] = sum_k A[m,k]*W[n,k] (+bias). 128x128 tile, 4 waves, BK=64, dbuf LDS.
// Per K-step: issue stage(t+1) -> s_waitcnt vmcnt(8) (tile t done, t+1 in flight)
// -> raw s_barrier -> ds_read+MFMA -> raw s_barrier. No vmcnt(0) drain in loop.
// Row-major block decomp (bx fast: A-panel reuse, W L2-resident) + XCD chunking.
// EPI: 1=bf16 store, 2=gelu->bf16, 3=per-head transposed V store ->bf16
template <int FM, int FN, int EPI>
__global__ __launch_bounds__(256) void gemm_k(
    const u16* __restrict__ A, const u16* __restrict__ W,
    const float* __restrict__ bias, void* __restrict__ C,
    int K, int lda, int ldw, int ldc, int NB, int TR) {
  constexpr int BM = 2 * FM * 16;
  constexpr int BN = 2 * FN * 16;
  __shared__ __align__(16) u16 Al[2][BM * 64];
  __shared__ __align__(16) u16 Wl[2][BN * 64];
  const int tid = threadIdx.x;
  // bijective XCD chunk swizzle (grids are multiples of 8), row-major decomp
  const int qq = gridDim.x >> 3;
  const int wg = (blockIdx.x & 7) * qq + (blockIdx.x >> 3);
  const int bx = wg % NB, by = wg / NB;
  const int row0 = by * BM, col0 = bx * BN;
  const int lane = tid & 63, wv = tid >> 6;
  const int wr = wv >> 1, wc = wv & 1;
  const int rowW = wr * FM * 16, colW = wc * FN * 16;
  const int lr = lane & 15, lg4 = lane >> 4;

  f32x4 acc[FM][FN] = {};
  const int NT = K >> 6;

  auto stage = [&](int bsel, int k0) {
    #pragma unroll
    for (int r = 0; r < BM / 32; ++r) {
      int o = r * 4096 + tid * 16;
      int arow = o >> 7, cd = (o >> 4) & 7, cs = cd ^ (arow & 7);
      g2l16((const char*)(A + (size_t)(row0 + arow) * lda + k0) + cs * 16,
            (char*)Al[bsel] + o);
    }
    #pragma unroll
    for (int r = 0; r < BN / 32; ++r) {
      int o = r * 4096 + tid * 16;
      int wrow = o >> 7, cd = (o >> 4) & 7, cs = cd ^ (wrow & 7);
      g2l16((const char*)(W + (size_t)(col0 + wrow) * ldw + k0) + cs * 16,
            (char*)Wl[bsel] + o);
    }
  };

  stage(0, 0);
  int cur = 0;
  for (int t = 0; t < NT; ++t) {
    if (t + 1 < NT) {
      stage(cur ^ 1, (t + 1) << 6);
      asm volatile("s_waitcnt vmcnt(8)" ::: "memory");
    } else {
      asm volatile("s_waitcnt vmcnt(0)" ::: "memory");
    }
    asm volatile("s_barrier" ::: "memory");  // tile t staged for all waves
    #pragma unroll
    for (int ks = 0; ks < 2; ++ks) {
      bfrag af[FM], wf[FN];
      #pragma unroll
      for (int m = 0; m < FM; ++m) {
        int rowi = rowW + m * 16 + lr;
        af[m] =
            *(const bfrag*)(Al[cur] + rowi * 64 + (((ks * 4 + lg4) ^ (rowi & 7)) * 8));
      }
      #pragma unroll
      for (int n = 0; n < FN; ++n) {
        int rowi = colW + n * 16 + lr;
        wf[n] =
            *(const bfrag*)(Wl[cur] + rowi * 64 + (((ks * 4 + lg4) ^ (rowi & 7)) * 8));
      }
      #pragma unroll
      for (int m = 0; m < FM; ++m)
        #pragma unroll
        for (int n = 0; n < FN; ++n) acc[m][n] = mfma16(af[m], wf[n], acc[m][n]);
    }
    asm volatile("s_barrier" ::: "memory");  // all waves done reading tile t
    cur ^= 1;
  }
  asm volatile("s_nop 7\n\ts_nop 7\n\ts_nop 7");

  #pragma unroll
  for (int m = 0; m < FM; ++m) {
    #pragma unroll
    for (int n = 0; n < FN; ++n) {
      int rb = row0 + rowW + m * 16 + lg4 * 4;
      int c = col0 + colW + n * 16 + lr;
      float bv = bias[c];
      if constexpr (EPI == 1) {
        u16* Cu = (u16*)C;
        #pragma unroll
        for (int e = 0; e < 4; ++e)
          Cu[(size_t)(rb + e) * ldc + c] = f2bf(acc[m][n][e] + bv);
      } else if constexpr (EPI == 2) {
        u16* Cu = (u16*)C;
        #pragma unroll
        for (int e = 0; e < 4; ++e) {
          float vv = acc[m][n][e] + bv;
          float gl = 0.5f * vv * (1.f + erff(vv * 0.70710678118f));
          Cu[(size_t)(rb + e) * ldc + c] = f2bf(gl);
        }
      } else {  // EPI == 3 : vt[((b*8+h)*64+d)*TR + j]
        u16* Cu = (u16*)C;
        int b2 = rb / TR, j0 = rb - b2 * TR;
        int h2 = c >> 6, dd = c & 63;
        ushort4 pk;
        pk.x = f2bf(acc[m][n][0] + bv);
        pk.y = f2bf(acc[m][n][1] + bv);
        pk.z = f2bf(acc[m][n][2] + bv);
        pk.w = f2bf(acc[m][n][3] + bv);
        *(ushort4*)&Cu[(((size_t)b2 * 8 + h2) * 64 + dd) * TR + j0] = pk;
      }
    }
  }
}

// =============================== host ===============================
extern "C" void kernel_launch(void* const* d_in, const int* in_sizes, int n_in,
                              void* d_out, int out_size, void* d_ws, size_t ws_size,
                              hipStream_t stream) {
  const float* h_d = (const float*)d_in[0];
  const float* h_p = (const float*)d_in[1];
  const float* gd_w = (const float*)d_in[2];
  const float* gd_b = (const float*)d_in[3];
  const float* gp_w = (const float*)d_in[4];
  const float* gp_b = (const float*)d_in[5];
  const float* wqd_w = (const float*)d_in[6];  const float* wqd_b = (const float*)d_in[7];
  const float* wkp_w = (const float*)d_in[8];  const float* wkp_b = (const float*)d_in[9];
  const float* wvp_w = (const float*)d_in[10]; const float* wvp_b = (const float*)d_in[11];
  const float* wqp_w = (const float*)d_in[12]; const float* wqp_b = (const float*)d_in[13];
  const float* wkd_w = (const float*)d_in[14]; const float* wkd_b = (const float*)d_in[15];
  const float* wvd_w = (const float*)d_in[16]; const float* wvd_b = (const float*)d_in[17];
  const float* od_w = (const float*)d_in[18];  const float* od_b = (const float*)d_in[19];
  const float* op_w = (const float*)d_in[20];  const float* op_b = (const float*)d_in[21];
  const float* fd1_w = (const float*)d_in[22]; const float* fd1_b = (const float*)d_in[23];
  const float* fd2_w = (const float*)d_in[24]; const float* fd2_b = (const float*)d_in[25];
  const float* fp1_w = (const float*)d_in[26]; const float* fp1_b = (const float*)d_in[27];
  const float* fp2_w = (const float*)d_in[28]; const float* fp2_b = (const float*)d_in[29];
  const float* nd1_s = (const float*)d_in[30]; const float* nd1_b = (const float*)d_in[31];
  const float* nd2_s = (const float*)d_in[32]; const float* nd2_b = (const float*)d_in[33];
  const float* np1_s = (const float*)d_in[34]; const float* np1_b = (const float*)d_in[35];
  const float* np2_s = (const float*)d_in[36]; const float* np2_b = (const float*)d_in[37];
  const int* mask_d = (const int*)d_in[38];
  const int* mask_p = (const int*)d_in[39];

  constexpr int B = 16, Ld = 256, Lp = 1024, D = 512, H = 8, F = 2048;
  constexpr int Md = B * Ld;   // 4096
  constexpr int Mp = B * Lp;   // 16384
  constexpr int BH = B * H;    // 128

  char* ws = (char*)d_ws;
  size_t off = 0;
  auto alloc = [&](size_t bytes) {
    size_t o = off;
    off += (bytes + 255) & ~(size_t)255;
    return o;
  };
  auto a16 = [&](size_t els) { return (u16*)(ws + alloc(els * 2)); };
  auto a32 = [&](size_t els) { return (float*)(ws + alloc(els * 4)); };

  u16* w_qd = a16((size_t)D * D);
  u16* w_kp = a16((size_t)D * D);
  u16* w_vp = a16((size_t)D * D);
  u16* w_qp = a16((size_t)D * D);
  u16* w_kd = a16((size_t)D * D);
  u16* w_vd = a16((size_t)D * D);
  u16* w_od = a16((size_t)D * D);
  u16* w_op = a16((size_t)D * D);
  u16* w_fd1 = a16((size_t)F * D);
  u16* w_fd2 = a16((size_t)F * D);
  u16* w_fp1 = a16((size_t)F * D);
  u16* w_fp2 = a16((size_t)F * D);

  u16* hd16 = a16((size_t)Md * D);     // h_d bf16 -> attn1 out
  u16* hd2_16 = a16((size_t)Md * D);   // h_d' (post LN1), residual for final LN
  u16* hp16 = a16((size_t)Mp * D);     // h_p bf16 -> attn2 out -> h_p'
  u16* qd16 = a16((size_t)Md * D);     // qd -> kd
  u16* kp16 = a16((size_t)Mp * D);     // kp -> qp
  u16* vt16 = a16((size_t)Mp * D);     // vp^T -> vd^T
  u16* obuf16 = a16((size_t)Mp * D);   // o-proj / ffn2 outputs (sequential lifetimes)
  u16* t16 = a16((size_t)Mp * F);      // ffn hidden (post-gelu)
  float* logg_d = a32(Md);
  float* logg_p = a32(Mp);

  // --- fused conversions (2 inputs + 12 weights) ---
  {
    CvtArgs a;
    const float* src[14] = {h_d, h_p, wqd_w, wkp_w, wvp_w, wqp_w, wkd_w,
                            wvd_w, od_w, op_w, fd1_w, fd2_w, fp1_w, fp2_w};
    u16* dst[14] = {hd16, hp16, w_qd, w_kp, w_vp, w_qp, w_kd,
                    w_vd, w_od, w_op, w_fd1, w_fd2, w_fp1, w_fp2};
    const int nelem[14] = {Md * D, Mp * D, D * D, D * D, D * D, D * D, D * D,
                           D * D, D * D, D * D, F * D, F * D, F * D, F * D};
    int pfx = 0;
    for (int i = 0; i < 14; ++i) {
      a.s[i] = src[i];
      a.d[i] = dst[i];
      pfx += nelem[i] / 1024;
      a.eb[i] = pfx;
    }
    cvt_all<<<pfx, 256, 0, stream>>>(a);
  }

  // --- gates (from ORIGINAL inputs) ---
  gate_k<<<(Md + Mp) / 4, 256, 0, stream>>>(h_d, h_p, gd_w, gd_b, gp_w, gp_b,
                                            logg_d, logg_p, Md);

  // --- projections for attn1 ---
  gemm_k<4, 4, 1><<<(Md / 128) * (D / 128), 256, 0, stream>>>(
      hd16, w_qd, wqd_b, qd16, D, D, D, D, D / 128, 0);
  gemm_k<4, 4, 1><<<(Mp / 128) * (D / 128), 256, 0, stream>>>(
      hp16, w_kp, wkp_b, kp16, D, D, D, D, D / 128, 0);
  gemm_k<4, 4, 3><<<(Mp / 128) * (D / 128), 256, 0, stream>>>(
      hp16, w_vp, wvp_b, vt16, D, D, D, 0, D / 128, Lp);

  // --- attn1: drug attends protein ---
  flash_k<128><<<dim3(Ld / 64, 1, BH), 256, 0, stream>>>(
      qd16, kp16, vt16, logg_p, mask_p, hd16, Ld, Lp, 0.125f);

  // --- o-proj + LN1 -> h_d' (bf16) ---
  gemm_k<4, 4, 1><<<(Md / 128) * (D / 128), 256, 0, stream>>>(
      hd16, w_od, od_b, obuf16, D, D, D, D, D / 128, 0);
  ln_k<0, 1><<<Md / 4, 256, 0, stream>>>(h_d, obuf16, nd1_s, nd1_b, hd2_16);

  // --- projections for attn2 (K/V from UPDATED drug) ---
  gemm_k<4, 4, 1><<<(Mp / 128) * (D / 128), 256, 0, stream>>>(
      hp16, w_qp, wqp_b, kp16, D, D, D, D, D / 128, 0);
  gemm_k<4, 4, 1><<<(Md / 128) * (D / 128), 256, 0, stream>>>(
      hd2_16, w_kd, wkd_b, qd16, D, D, D, D, D / 128, 0);
  gemm_k<4, 4, 3><<<(Md / 128) * (D / 128), 256, 0, stream>>>(
      hd2_16, w_vd, wvd_b, vt16, D, D, D, 0, D / 128, Ld);

  // --- attn2: protein attends drug ---
  flash_k<128><<<dim3(Lp / 64, 1, BH), 256, 0, stream>>>(
      kp16, qd16, vt16, logg_d, mask_d, hp16, Lp, Ld, 0.125f);

  // --- o-proj + LN2 -> h_p' (bf16, into hp16) ---
  gemm_k<4, 4, 1><<<(Mp / 128) * (D / 128), 256, 0, stream>>>(
      hp16, w_op, op_b, obuf16, D, D, D, D, D / 128, 0);
  ln_k<0, 1><<<Mp / 4, 256, 0, stream>>>(h_p, obuf16, np1_s, np1_b, hp16);

  // --- FFN drug + final LN -> d_out[0 : Md*D] ---
  gemm_k<4, 4, 2><<<(Md / 128) * (F / 128), 256, 0, stream>>>(
      hd2_16, w_fd1, fd1_b, t16, D, D, D, F, F / 128, 0);
  gemm_k<4, 4, 1><<<(Md / 128) * (D / 128), 256, 0, stream>>>(
      t16, w_fd2, fd2_b, obuf16, F, F, F, D, D / 128, 0);
  ln_k<1, 0><<<Md / 4, 256, 0, stream>>>(hd2_16, obuf16, nd2_s, nd2_b, (float*)d_out);

  // --- FFN protein + final LN -> d_out[Md*D : ] ---
  gemm_k<4, 4, 2><<<(Mp / 128) * (F / 128), 256, 0, stream>>>(
      hp16, w_fp1, fp1_b, t16, D, D, D, F, F / 128, 0);
  gemm_k<4, 4, 1><<<(Mp / 128) * (D / 128), 256, 0, stream>>>(
      t16, w_fp2, fp2_b, obuf16, F, F, F, D, D / 128, 0);
  ln_k<1, 0><<<Mp / 4, 256, 0, stream>>>(hp16, obuf16, np2_s, np2_b,
                                         (float*)d_out + (size_t)Md * D);
}

// Round 5
// 390.256 us; speedup vs baseline: 2.5537x; 1.0109x over previous
//
#include <hip/hip_runtime.h>

typedef float f32x4 __attribute__((ext_vector_type(4)));
typedef short bfrag __attribute__((ext_vector_type(8)));
typedef short s16x8 __attribute__((ext_vector_type(8)));
typedef unsigned short u16;

__device__ __forceinline__ u16 f2bf(float f) {
  union { float f; unsigned u; } x; x.f = f;
  unsigned r = x.u + 0x7fffu + ((x.u >> 16) & 1u);
  return (u16)(r >> 16);
}
__device__ __forceinline__ float bf2f(u16 v) {
  union { unsigned u; float f; } x; x.u = ((unsigned)v) << 16;
  return x.f;
}

__device__ __forceinline__ void g2l16(const void* g, void* l) {
  void* gnc = const_cast<void*>(g);
  __builtin_amdgcn_global_load_lds((__attribute__((address_space(1))) void*)gnc,
                                   (__attribute__((address_space(3))) void*)l, 16, 0, 0);
}

__device__ __forceinline__ f32x4 mfma16(bfrag a, bfrag b, f32x4 c) {
  asm volatile("v_mfma_f32_16x16x32_bf16 %0, %1, %2, %0" : "+v"(c) : "v"(a), "v"(b));
  return c;
}

__device__ __forceinline__ float wred_sum(float s) {
  #pragma unroll
  for (int o = 32; o; o >>= 1) s += __shfl_xor(s, o);
  return s;
}

// ---------------- fused f32 -> bf16 convert (all 14 tensors, 1 launch) ----------------
struct CvtArgs {
  const float* s[14];
  u16* d[14];
  int eb[14];  // inclusive prefix of block counts
};

__global__ __launch_bounds__(256) void cvt_all(CvtArgs a) {
  const int blk = blockIdx.x;
  int base = 0;
  const float* sp = a.s[0];
  u16* dp = a.d[0];
  #pragma unroll
  for (int i = 0; i < 13; ++i) {
    if (blk >= a.eb[i]) { base = a.eb[i]; sp = a.s[i + 1]; dp = a.d[i + 1]; }
  }
  const size_t gi = ((size_t)(blk - base) * 256 + threadIdx.x) * 4;
  float4 f = *(const float4*)(sp + gi);
  ushort4 o;
  o.x = f2bf(f.x); o.y = f2bf(f.y); o.z = f2bf(f.z); o.w = f2bf(f.w);
  *(ushort4*)(dp + gi) = o;
}

// ---------------- uncertainty gates (both tensors, 1 launch) ----------------
__device__ __forceinline__ float softplus_s(float x) {
  return fmaxf(x, 0.f) + log1pf(expf(-fabsf(x)));
}

__global__ __launch_bounds__(256) void gate_k(
    const float* __restrict__ hd, const float* __restrict__ hp,
    const float* __restrict__ wd, const float* __restrict__ bd,
    const float* __restrict__ wp, const float* __restrict__ bp,
    float* __restrict__ lgd, float* __restrict__ lgp, int mdTok) {
  const int lane = threadIdx.x & 63, wv = threadIdx.x >> 6;
  size_t tok = (size_t)blockIdx.x * 4 + wv;
  const float* h; const float* w4; const float* b4; float* lg;
  if (tok < (size_t)mdTok) { h = hd; w4 = wd; b4 = bd; lg = lgd; }
  else { h = hp; w4 = wp; b4 = bp; lg = lgp; tok -= mdTok; }
  const float* x = h + tok * 512;
  float s0 = 0.f, s1 = 0.f, s2 = 0.f, s3 = 0.f;
  #pragma unroll
  for (int i = 0; i < 8; ++i) {
    int c = (i << 6) + lane;
    float xv = x[c];
    s0 += xv * w4[c];
    s1 += xv * w4[512 + c];
    s2 += xv * w4[1024 + c];
    s3 += xv * w4[1536 + c];
  }
  s0 = wred_sum(s0); s1 = wred_sum(s1); s2 = wred_sum(s2); s3 = wred_sum(s3);
  if (lane == 0) {
    float mu = s0 + b4[0];
    float va = softplus_s(s1 + b4[1]) + 1e-6f;
    float al = softplus_s(s2 + b4[2]) + 1.f + 1e-6f;
    float be = softplus_s(s3 + b4[3]) + 1e-6f;
    float se2 = be / (va * (al - 1.f));
    float g = (1.f / (1.f + expf(-mu))) * expf(-se2);
    g = fminf(fmaxf(g, 1e-3f), 1.f);
    lg[tok] = logf(g + 1e-9f);
  }
}

// ---------------- residual + LayerNorm (RES: 0=f32,1=bf16; OUT: 0=f32,1=bf16) ----------------
template <int RES, int OUT>
__global__ __launch_bounds__(256) void ln_k(const void* __restrict__ resv,
                                            const u16* __restrict__ y,
                                            const float* __restrict__ sc,
                                            const float* __restrict__ bi,
                                            void* __restrict__ outv) {
  const int lane = threadIdx.x & 63, w = threadIdx.x >> 6;
  const size_t row = (size_t)blockIdx.x * 4 + w;
  const int c0 = lane * 8;
  float v[8];
  s16x8 yv = *(const s16x8*)(y + row * 512 + c0);
  if constexpr (RES == 0) {
    const float* rf = (const float*)resv + row * 512 + c0;
    float4 r0 = *(const float4*)rf, r1 = *(const float4*)(rf + 4);
    v[0] = r0.x; v[1] = r0.y; v[2] = r0.z; v[3] = r0.w;
    v[4] = r1.x; v[5] = r1.y; v[6] = r1.z; v[7] = r1.w;
  } else {
    s16x8 rv = *(const s16x8*)((const u16*)resv + row * 512 + c0);
    #pragma unroll
    for (int i = 0; i < 8; ++i) v[i] = bf2f((u16)rv[i]);
  }
  float s = 0.f;
  #pragma unroll
  for (int i = 0; i < 8; ++i) { v[i] += bf2f((u16)yv[i]); s += v[i]; }
  s = wred_sum(s);
  float m = s * (1.f / 512.f);
  float s2 = 0.f;
  #pragma unroll
  for (int i = 0; i < 8; ++i) { float d = v[i] - m; s2 += d * d; }
  s2 = wred_sum(s2);
  float inv = rsqrtf(s2 * (1.f / 512.f) + 1e-5f);
  float4 sc0 = *(const float4*)(sc + c0), sc1 = *(const float4*)(sc + c0 + 4);
  float4 bi0 = *(const float4*)(bi + c0), bi1 = *(const float4*)(bi + c0 + 4);
  float scv[8] = {sc0.x, sc0.y, sc0.z, sc0.w, sc1.x, sc1.y, sc1.z, sc1.w};
  float biv[8] = {bi0.x, bi0.y, bi0.z, bi0.w, bi1.x, bi1.y, bi1.z, bi1.w};
  float o[8];
  #pragma unroll
  for (int i = 0; i < 8; ++i) o[i] = (v[i] - m) * inv * scv[i] + biv[i];
  if constexpr (OUT == 0) {
    float* of = (float*)outv + row * 512 + c0;
    *(float4*)of = float4{o[0], o[1], o[2], o[3]};
    *(float4*)(of + 4) = float4{o[4], o[5], o[6], o[7]};
  } else {
    s16x8 ov;
    #pragma unroll
    for (int i = 0; i < 8; ++i) ov[i] = (short)f2bf(o[i]);
    *(s16x8*)((u16*)outv + row * 512 + c0) = ov;
  }
}

// ---------------- fused flash cross-attention ----------------
template <int KT>
__global__ __launch_bounds__(256) void flash_k(
    const u16* __restrict__ Q, const u16* __restrict__ Kv,
    const u16* __restrict__ Vt, const float* __restrict__ logg,
    const int* __restrict__ mask, u16* __restrict__ Out,
    int Lq, int Lk, float scale) {
  __shared__ __align__(16) u16 Kl[KT * 64];
  __shared__ __align__(16) u16 Vl[64 * KT];
  __shared__ __align__(16) u16 Pl[64 * (KT + 8)];
  const int tid = threadIdx.x;
  const int lane = tid & 63, wv = tid >> 6;
  const int lr = lane & 15, lg4 = lane >> 4;
  const int bh = blockIdx.z;
  const int b = bh >> 3, h = bh & 7;
  const int q0 = blockIdx.x * 64;

  bfrag af[2];
  {
    const u16* qrow = Q + (size_t)(b * Lq + q0 + wv * 16 + lr) * 512 + h * 64;
    af[0] = *(const bfrag*)(qrow + lg4 * 8);
    af[1] = *(const bfrag*)(qrow + 32 + lg4 * 8);
  }
  float mreg[4] = {-3e38f, -3e38f, -3e38f, -3e38f};
  float lreg[4] = {0.f, 0.f, 0.f, 0.f};
  f32x4 Oa[4] = {};
  const float* lgb = logg + (size_t)b * Lk;
  const int* mkb = mask + (size_t)b * Lk;

  const int NKT = Lk / KT;
  for (int t = 0; t < NKT; ++t) {
    const int k0 = t * KT;
    __syncthreads();
    {
      const char* kb = (const char*)(Kv + (size_t)(b * Lk + k0) * 512 + h * 64);
      #pragma unroll
      for (int r = 0; r < KT / 32; ++r) {
        int o = r * 4096 + tid * 16;
        int rr = o >> 7, cd = (o >> 4) & 7;
        int cs = cd ^ (rr & 7);
        g2l16(kb + (size_t)rr * 1024 + cs * 16, (char*)Kl + o);
      }
      const char* vb = (const char*)(Vt + (size_t)bh * 64 * Lk + k0);
      #pragma unroll
      for (int r = 0; r < KT / 32; ++r) {
        int o = r * 4096 + tid * 16;
        int rr = o >> 8, cd = (o >> 4) & 15;
        int cs = (cd & 8) | ((cd & 7) ^ (rr & 7));
        g2l16(vb + (size_t)rr * (Lk * 2) + cs * 16, (char*)Vl + o);
      }
    }
    __syncthreads();

    f32x4 sa[KT / 16];
    #pragma unroll
    for (int n = 0; n < KT / 16; ++n) {
      sa[n] = f32x4{0.f, 0.f, 0.f, 0.f};
      int row = n * 16 + lr;
      #pragma unroll
      for (int ks = 0; ks < 2; ++ks) {
        bfrag kf = *(const bfrag*)(Kl + row * 64 + (((ks * 4 + lg4) ^ (row & 7)) * 8));
        sa[n] = mfma16(af[ks], kf, sa[n]);
      }
    }
    asm volatile("s_nop 7\n\ts_nop 7");

    float pv[KT / 16][4];
    float nm[4] = {-3e38f, -3e38f, -3e38f, -3e38f};
    #pragma unroll
    for (int n = 0; n < KT / 16; ++n) {
      int kk = k0 + n * 16 + lr;
      float lgv = lgb[kk];
      int mkv = mkb[kk];
      #pragma unroll
      for (int e = 0; e < 4; ++e) {
        float tv = mkv ? fmaf(sa[n][e], scale, lgv) : -1e9f;
        pv[n][e] = tv;
        nm[e] = fmaxf(nm[e], tv);
      }
    }
    float fac[4], rs[4];
    #pragma unroll
    for (int e = 0; e < 4; ++e) {
      nm[e] = fmaxf(nm[e], __shfl_xor(nm[e], 1));
      nm[e] = fmaxf(nm[e], __shfl_xor(nm[e], 2));
      nm[e] = fmaxf(nm[e], __shfl_xor(nm[e], 4));
      nm[e] = fmaxf(nm[e], __shfl_xor(nm[e], 8));
      nm[e] = fmaxf(nm[e], mreg[e]);
      fac[e] = __expf(mreg[e] - nm[e]);
      mreg[e] = nm[e];
      rs[e] = 0.f;
    }
    #pragma unroll
    for (int n = 0; n < KT / 16; ++n)
      #pragma unroll
      for (int e = 0; e < 4; ++e) {
        float p = __expf(pv[n][e] - nm[e]);
        pv[n][e] = p;
        rs[e] += p;
      }
    #pragma unroll
    for (int e = 0; e < 4; ++e) {
      rs[e] += __shfl_xor(rs[e], 1);
      rs[e] += __shfl_xor(rs[e], 2);
      rs[e] += __shfl_xor(rs[e], 4);
      rs[e] += __shfl_xor(rs[e], 8);
      lreg[e] = lreg[e] * fac[e] + rs[e];
    }
    #pragma unroll
    for (int n2 = 0; n2 < 4; ++n2)
      #pragma unroll
      for (int e = 0; e < 4; ++e) Oa[n2][e] *= fac[e];

    {
      int prow = wv * 16 + lg4 * 4;
      #pragma unroll
      for (int n = 0; n < KT / 16; ++n)
        #pragma unroll
        for (int e = 0; e < 4; ++e)
          Pl[(prow + e) * (KT + 8) + n * 16 + lr] = f2bf(pv[n][e]);
    }
    #pragma unroll
    for (int ks = 0; ks < KT / 32; ++ks) {
      bfrag pf = *(const bfrag*)(Pl + (wv * 16 + lr) * (KT + 8) + (ks * 4 + lg4) * 8);
      #pragma unroll
      for (int n2 = 0; n2 < 4; ++n2) {
        int vrow = n2 * 16 + lr;
        int ch = ks * 4 + lg4;
        int chs = (ch & 8) | ((ch & 7) ^ (vrow & 7));
        bfrag vf = *(const bfrag*)(Vl + vrow * KT + chs * 8);
        Oa[n2] = mfma16(pf, vf, Oa[n2]);
      }
    }
  }
  asm volatile("s_nop 7\n\ts_nop 7");

  float inv[4];
  #pragma unroll
  for (int e = 0; e < 4; ++e) inv[e] = 1.f / lreg[e];
  u16* ob = Out + (size_t)(b * Lq + q0 + wv * 16 + lg4 * 4) * 512 + h * 64;
  #pragma unroll
  for (int n2 = 0; n2 < 4; ++n2)
    #pragma unroll
    for (int e = 0; e < 4; ++e)
      ob[(size_t)e * 512 + n2 * 16 + lr] = f2bf(Oa[n2][e] * inv[e]);
}

// ---------------- m97-structure MFMA GEMM: C[m,n] = sum_k A[m,k]*W[n,k] (+bias) ----------------
// 128x128 tile, 4 waves, BK=64, SINGLE-buffered 32KB LDS, 2x __syncthreads per K-step
// (compiler-managed waits; implicit inter-block wave overlap at ~4-5 blocks/CU does the
// pipelining — m97/m114). XOR-swizzled LDS (conflict-free), row-reuse + XCD-bijective order.
// EPI: 1=bf16 store, 2=gelu->bf16, 3=per-head transposed V store ->bf16
template <int FM, int FN, int EPI>
__global__ __launch_bounds__(256) void gemm_k(
    const u16* __restrict__ A, const u16* __restrict__ W,
    const float* __restrict__ bias, void* __restrict__ C,
    int K, int lda, int ldw, int ldc, int NB, int TR) {
  constexpr int BM = 2 * FM * 16;  // 128
  constexpr int BN = 2 * FN * 16;  // 128
  __shared__ __align__(16) u16 Al[BM * 64];
  __shared__ __align__(16) u16 Wl[BN * 64];
  const int tid = threadIdx.x;
  // bijective XCD chunk swizzle (grids are multiples of 8), row-major decomp (bx fast)
  const int qq = gridDim.x >> 3;
  const int wg = (blockIdx.x & 7) * qq + (blockIdx.x >> 3);
  const int bx = wg % NB, by = wg / NB;
  const int row0 = by * BM, col0 = bx * BN;
  const int lane = tid & 63, wv = tid >> 6;
  const int wr = wv >> 1, wc = wv & 1;
  const int rowW = wr * FM * 16, colW = wc * FN * 16;
  const int lr = lane & 15, lg4 = lane >> 4;

  // hoisted per-thread staging sources (advance by k each step)
  const u16* aSrc[BM / 32];
  const u16* wSrc[BN / 32];
  int aDst[BM / 32], wDst[BN / 32];
  #pragma unroll
  for (int r = 0; r < BM / 32; ++r) {
    int o = r * 4096 + tid * 16;
    int arow = o >> 7, cd = (o >> 4) & 7, cs = cd ^ (arow & 7);
    aSrc[r] = A + (size_t)(row0 + arow) * lda + cs * 8;
    aDst[r] = o;
  }
  #pragma unroll
  for (int r = 0; r < BN / 32; ++r) {
    int o = r * 4096 + tid * 16;
    int wrow = o >> 7, cd = (o >> 4) & 7, cs = cd ^ (wrow & 7);
    wSrc[r] = W + (size_t)(col0 + wrow) * ldw + cs * 8;
    wDst[r] = o;
  }
  // hoisted LDS fragment byte offsets
  int aOff[FM][2], wOff[FN][2];
  #pragma unroll
  for (int m = 0; m < FM; ++m) {
    int rowi = rowW + m * 16 + lr;
    #pragma unroll
    for (int ks = 0; ks < 2; ++ks)
      aOff[m][ks] = rowi * 64 + (((ks * 4 + lg4) ^ (rowi & 7)) * 8);
  }
  #pragma unroll
  for (int n = 0; n < FN; ++n) {
    int rowi = colW + n * 16 + lr;
    #pragma unroll
    for (int ks = 0; ks < 2; ++ks)
      wOff[n][ks] = rowi * 64 + (((ks * 4 + lg4) ^ (rowi & 7)) * 8);
  }

  f32x4 acc[FM][FN] = {};

  for (int k0 = 0; k0 < K; k0 += 64) {
    #pragma unroll
    for (int r = 0; r < BM / 32; ++r) g2l16(aSrc[r] + k0, (char*)Al + aDst[r]);
    #pragma unroll
    for (int r = 0; r < BN / 32; ++r) g2l16(wSrc[r] + k0, (char*)Wl + wDst[r]);
    __syncthreads();
    #pragma unroll
    for (int ks = 0; ks < 2; ++ks) {
      bfrag af[FM], wf[FN];
      #pragma unroll
      for (int m = 0; m < FM; ++m) af[m] = *(const bfrag*)(Al + aOff[m][ks]);
      #pragma unroll
      for (int n = 0; n < FN; ++n) wf[n] = *(const bfrag*)(Wl + wOff[n][ks]);
      #pragma unroll
      for (int m = 0; m < FM; ++m)
        #pragma unroll
        for (int n = 0; n < FN; ++n) acc[m][n] = mfma16(af[m], wf[n], acc[m][n]);
    }
    __syncthreads();
  }
  asm volatile("s_nop 7\n\ts_nop 7\n\ts_nop 7");

  #pragma unroll
  for (int m = 0; m < FM; ++m) {
    #pragma unroll
    for (int n = 0; n < FN; ++n) {
      int rb = row0 + rowW + m * 16 + lg4 * 4;
      int c = col0 + colW + n * 16 + lr;
      float bv = bias[c];
      if constexpr (EPI == 1) {
        u16* Cu = (u16*)C;
        #pragma unroll
        for (int e = 0; e < 4; ++e)
          Cu[(size_t)(rb + e) * ldc + c] = f2bf(acc[m][n][e] + bv);
      } else if constexpr (EPI == 2) {
        u16* Cu = (u16*)C;
        #pragma unroll
        for (int e = 0; e < 4; ++e) {
          float vv = acc[m][n][e] + bv;
          float gl = 0.5f * vv * (1.f + erff(vv * 0.70710678118f));
          Cu[(size_t)(rb + e) * ldc + c] = f2bf(gl);
        }
      } else {  // EPI == 3 : vt[((b*8+h)*64+d)*TR + j]
        u16* Cu = (u16*)C;
        int b2 = rb / TR, j0 = rb - b2 * TR;
        int h2 = c >> 6, dd = c & 63;
        ushort4 pk;
        pk.x = f2bf(acc[m][n][0] + bv);
        pk.y = f2bf(acc[m][n][1] + bv);
        pk.z = f2bf(acc[m][n][2] + bv);
        pk.w = f2bf(acc[m][n][3] + bv);
        *(ushort4*)&Cu[(((size_t)b2 * 8 + h2) * 64 + dd) * TR + j0] = pk;
      }
    }
  }
}

// =============================== host ===============================
extern "C" void kernel_launch(void* const* d_in, const int* in_sizes, int n_in,
                              void* d_out, int out_size, void* d_ws, size_t ws_size,
                              hipStream_t stream) {
  const float* h_d = (const float*)d_in[0];
  const float* h_p = (const float*)d_in[1];
  const float* gd_w = (const float*)d_in[2];
  const float* gd_b = (const float*)d_in[3];
  const float* gp_w = (const float*)d_in[4];
  const float* gp_b = (const float*)d_in[5];
  const float* wqd_w = (const float*)d_in[6];  const float* wqd_b = (const float*)d_in[7];
  const float* wkp_w = (const float*)d_in[8];  const float* wkp_b = (const float*)d_in[9];
  const float* wvp_w = (const float*)d_in[10]; const float* wvp_b = (const float*)d_in[11];
  const float* wqp_w = (const float*)d_in[12]; const float* wqp_b = (const float*)d_in[13];
  const float* wkd_w = (const float*)d_in[14]; const float* wkd_b = (const float*)d_in[15];
  const float* wvd_w = (const float*)d_in[16]; const float* wvd_b = (const float*)d_in[17];
  const float* od_w = (const float*)d_in[18];  const float* od_b = (const float*)d_in[19];
  const float* op_w = (const float*)d_in[20];  const float* op_b = (const float*)d_in[21];
  const float* fd1_w = (const float*)d_in[22]; const float* fd1_b = (const float*)d_in[23];
  const float* fd2_w = (const float*)d_in[24]; const float* fd2_b = (const float*)d_in[25];
  const float* fp1_w = (const float*)d_in[26]; const float* fp1_b = (const float*)d_in[27];
  const float* fp2_w = (const float*)d_in[28]; const float* fp2_b = (const float*)d_in[29];
  const float* nd1_s = (const float*)d_in[30]; const float* nd1_b = (const float*)d_in[31];
  const float* nd2_s = (const float*)d_in[32]; const float* nd2_b = (const float*)d_in[33];
  const float* np1_s = (const float*)d_in[34]; const float* np1_b = (const float*)d_in[35];
  const float* np2_s = (const float*)d_in[36]; const float* np2_b = (const float*)d_in[37];
  const int* mask_d = (const int*)d_in[38];
  const int* mask_p = (const int*)d_in[39];

  constexpr int B = 16, Ld = 256, Lp = 1024, D = 512, H = 8, F = 2048;
  constexpr int Md = B * Ld;   // 4096
  constexpr int Mp = B * Lp;   // 16384
  constexpr int BH = B * H;    // 128

  char* ws = (char*)d_ws;
  size_t off = 0;
  auto alloc = [&](size_t bytes) {
    size_t o = off;
    off += (bytes + 255) & ~(size_t)255;
    return o;
  };
  auto a16 = [&](size_t els) { return (u16*)(ws + alloc(els * 2)); };
  auto a32 = [&](size_t els) { return (float*)(ws + alloc(els * 4)); };

  u16* w_qd = a16((size_t)D * D);
  u16* w_kp = a16((size_t)D * D);
  u16* w_vp = a16((size_t)D * D);
  u16* w_qp = a16((size_t)D * D);
  u16* w_kd = a16((size_t)D * D);
  u16* w_vd = a16((size_t)D * D);
  u16* w_od = a16((size_t)D * D);
  u16* w_op = a16((size_t)D * D);
  u16* w_fd1 = a16((size_t)F * D);
  u16* w_fd2 = a16((size_t)F * D);
  u16* w_fp1 = a16((size_t)F * D);
  u16* w_fp2 = a16((size_t)F * D);

  u16* hd16 = a16((size_t)Md * D);     // h_d bf16 -> attn1 out
  u16* hd2_16 = a16((size_t)Md * D);   // h_d' (post LN1), residual for final LN
  u16* hp16 = a16((size_t)Mp * D);     // h_p bf16 -> attn2 out -> h_p'
  u16* qd16 = a16((size_t)Md * D);     // qd -> kd
  u16* kp16 = a16((size_t)Mp * D);     // kp -> qp
  u16* vt16 = a16((size_t)Mp * D);     // vp^T -> vd^T
  u16* obuf16 = a16((size_t)Mp * D);   // o-proj / ffn2 outputs (sequential lifetimes)
  u16* t16 = a16((size_t)Mp * F);      // ffn hidden (post-gelu)
  float* logg_d = a32(Md);
  float* logg_p = a32(Mp);

  // --- fused conversions (2 inputs + 12 weights) ---
  {
    CvtArgs a;
    const float* src[14] = {h_d, h_p, wqd_w, wkp_w, wvp_w, wqp_w, wkd_w,
                            wvd_w, od_w, op_w, fd1_w, fd2_w, fp1_w, fp2_w};
    u16* dst[14] = {hd16, hp16, w_qd, w_kp, w_vp, w_qp, w_kd,
                    w_vd, w_od, w_op, w_fd1, w_fd2, w_fp1, w_fp2};
    const int nelem[14] = {Md * D, Mp * D, D * D, D * D, D * D, D * D, D * D,
                           D * D, D * D, D * D, F * D, F * D, F * D, F * D};
    int pfx = 0;
    for (int i = 0; i < 14; ++i) {
      a.s[i] = src[i];
      a.d[i] = dst[i];
      pfx += nelem[i] / 1024;
      a.eb[i] = pfx;
    }
    cvt_all<<<pfx, 256, 0, stream>>>(a);
  }

  // --- gates (from ORIGINAL inputs) ---
  gate_k<<<(Md + Mp) / 4, 256, 0, stream>>>(h_d, h_p, gd_w, gd_b, gp_w, gp_b,
                                            logg_d, logg_p, Md);

  // --- projections for attn1 ---
  gemm_k<4, 4, 1><<<(Md / 128) * (D / 128), 256, 0, stream>>>(
      hd16, w_qd, wqd_b, qd16, D, D, D, D, D / 128, 0);
  gemm_k<4, 4, 1><<<(Mp / 128) * (D / 128), 256, 0, stream>>>(
      hp16, w_kp, wkp_b, kp16, D, D, D, D, D / 128, 0);
  gemm_k<4, 4, 3><<<(Mp / 128) * (D / 128), 256, 0, stream>>>(
      hp16, w_vp, wvp_b, vt16, D, D, D, 0, D / 128, Lp);

  // --- attn1: drug attends protein ---
  flash_k<128><<<dim3(Ld / 64, 1, BH), 256, 0, stream>>>(
      qd16, kp16, vt16, logg_p, mask_p, hd16, Ld, Lp, 0.125f);

  // --- o-proj + LN1 -> h_d' (bf16) ---
  gemm_k<4, 4, 1><<<(Md / 128) * (D / 128), 256, 0, stream>>>(
      hd16, w_od, od_b, obuf16, D, D, D, D, D / 128, 0);
  ln_k<0, 1><<<Md / 4, 256, 0, stream>>>(h_d, obuf16, nd1_s, nd1_b, hd2_16);

  // --- projections for attn2 (K/V from UPDATED drug) ---
  gemm_k<4, 4, 1><<<(Mp / 128) * (D / 128), 256, 0, stream>>>(
      hp16, w_qp, wqp_b, kp16, D, D, D, D, D / 128, 0);
  gemm_k<4, 4, 1><<<(Md / 128) * (D / 128), 256, 0, stream>>>(
      hd2_16, w_kd, wkd_b, qd16, D, D, D, D, D / 128, 0);
  gemm_k<4, 4, 3><<<(Md / 128) * (D / 128), 256, 0, stream>>>(
      hd2_16, w_vd, wvd_b, vt16, D, D, D, 0, D / 128, Ld);

  // --- attn2: protein attends drug ---
  flash_k<128><<<dim3(Lp / 64, 1, BH), 256, 0, stream>>>(
      kp16, qd16, vt16, logg_d, mask_d, hp16, Lp, Ld, 0.125f);

  // --- o-proj + LN2 -> h_p' (bf16, into hp16) ---
  gemm_k<4, 4, 1><<<(Mp / 128) * (D / 128), 256, 0, stream>>>(
      hp16, w_op, op_b, obuf16, D, D, D, D, D / 128, 0);
  ln_k<0, 1><<<Mp / 4, 256, 0, stream>>>(h_p, obuf16, np1_s, np1_b, hp16);

  // --- FFN drug + final LN -> d_out[0 : Md*D] ---
  gemm_k<4, 4, 2><<<(Md / 128) * (F / 128), 256, 0, stream>>>(
      hd2_16, w_fd1, fd1_b, t16, D, D, D, F, F / 128, 0);
  gemm_k<4, 4, 1><<<(Md / 128) * (D / 128), 256, 0, stream>>>(
      t16, w_fd2, fd2_b, obuf16, F, F, F, D, D / 128, 0);
  ln_k<1, 0><<<Md / 4, 256, 0, stream>>>(hd2_16, obuf16, nd2_s, nd2_b, (float*)d_out);

  // --- FFN protein + final LN -> d_out[Md*D : ] ---
  gemm_k<4, 4, 2><<<(Mp / 128) * (F / 128), 256, 0, stream>>>(
      hp16, w_fp1, fp1_b, t16, D, D, D, F, F / 128, 0);
  gemm_k<4, 4, 1><<<(Mp / 128) * (D / 128), 256, 0, stream>>>(
      t16, w_fp2, fp2_b, obuf16, F, F, F, D, D / 128, 0);
  ln_k<1, 0><<<Mp / 4, 256, 0, stream>>>(hp16, obuf16, np2_s, np2_b,
                                         (float*)d_out + (size_t)Md * D);
}